// Round 2
// baseline (5629.611 us; speedup 1.0000x reference)
//
#include <hip/hip_runtime.h>

#define N_NODES 100000
#define N_EDGES 3200000
#define IN_CH 256
#define HID 16
#define OUT_CH 40

// ---------------- degree: deg[col] += 1 ----------------
__global__ void deg_kernel(const int* __restrict__ col, float* __restrict__ deg, int E) {
    int e = blockIdx.x * blockDim.x + threadIdx.x;
    if (e < E) atomicAdd(&deg[col[e]], 1.0f);
}

// ---------------- dinv = rsqrt(deg + 1) in place ----------------
__global__ void dinv_kernel(float* __restrict__ deg, int N) {
    int i = blockIdx.x * blockDim.x + threadIdx.x;
    if (i < N) deg[i] = rsqrtf(deg[i] + 1.0f);
}

// ---------------- h1 = x @ W1   [N,256]@[256,16] ----------------
__global__ void gemm1_kernel(const float* __restrict__ x, const float* __restrict__ W1,
                             float* __restrict__ h1, int N) {
    __shared__ float Ws[IN_CH * HID];   // 16 KB
    for (int i = threadIdx.x; i < IN_CH * HID; i += blockDim.x) Ws[i] = W1[i];
    __syncthreads();
    int r = blockIdx.x * blockDim.x + threadIdx.x;
    if (r >= N) return;
    float acc[HID];
#pragma unroll
    for (int j = 0; j < HID; ++j) acc[j] = 0.f;
    const float4* xr = (const float4*)(x + (size_t)r * IN_CH);
#pragma unroll 4
    for (int c = 0; c < IN_CH / 4; ++c) {
        float4 v = xr[c];
        const float* w = &Ws[c * 4 * HID];
#pragma unroll
        for (int j = 0; j < HID; ++j)
            acc[j] += v.x * w[j] + v.y * w[HID + j] + v.z * w[2 * HID + j] + v.w * w[3 * HID + j];
    }
    float* o = h1 + (size_t)r * HID;
#pragma unroll
    for (int j = 0; j < HID; j += 4)
        *(float4*)(o + j) = make_float4(acc[j], acc[j + 1], acc[j + 2], acc[j + 3]);
}

// ---------------- scatter: dst[col] += src[row] * dinv[row]*dinv[col], 16-wide ----------------
__global__ void scatter16_kernel(const int* __restrict__ row, const int* __restrict__ col,
                                 const float* __restrict__ dinv, const float* __restrict__ src,
                                 float* __restrict__ dst, int E) {
    int e = blockIdx.x * blockDim.x + threadIdx.x;
    if (e >= E) return;
    int r = row[e], c = col[e];
    float nrm = dinv[r] * dinv[c];
    const float4* s = (const float4*)(src + (size_t)r * HID);
    float* d = dst + (size_t)c * HID;
#pragma unroll
    for (int q = 0; q < 4; ++q) {
        float4 v = s[q];
        atomicAdd(&d[4 * q + 0], v.x * nrm);
        atomicAdd(&d[4 * q + 1], v.y * nrm);
        atomicAdd(&d[4 * q + 2], v.z * nrm);
        atomicAdd(&d[4 * q + 3], v.w * nrm);
    }
}

// ---------------- h = relu(a1 + h1*dinv^2 + b1), in place over h1 ----------------
__global__ void relu_kernel(float* __restrict__ h1, const float* __restrict__ a1,
                            const float* __restrict__ dinv, const float* __restrict__ b1, int N) {
    int i = blockIdx.x * blockDim.x + threadIdx.x;
    if (i >= N) return;
    float sn = dinv[i] * dinv[i];
    float* h = h1 + (size_t)i * HID;
    const float* a = a1 + (size_t)i * HID;
#pragma unroll
    for (int q = 0; q < 4; ++q) {
        float4 hv = *(const float4*)(h + 4 * q);
        float4 av = *(const float4*)(a + 4 * q);
        float4 rv;
        rv.x = fmaxf(av.x + hv.x * sn + b1[4 * q + 0], 0.f);
        rv.y = fmaxf(av.y + hv.y * sn + b1[4 * q + 1], 0.f);
        rv.z = fmaxf(av.z + hv.z * sn + b1[4 * q + 2], 0.f);
        rv.w = fmaxf(av.w + hv.w * sn + b1[4 * q + 3], 0.f);
        *(float4*)(h + 4 * q) = rv;
    }
}

// ---------------- out = log_softmax((a2 + h*dinv^2) @ W2 + b2) ----------------
__global__ void final_kernel(const float* __restrict__ a2, const float* __restrict__ h,
                             const float* __restrict__ dinv, const float* __restrict__ W2,
                             const float* __restrict__ b2, float* __restrict__ out, int N) {
    __shared__ float Ws[HID * OUT_CH];  // 2.5 KB
    __shared__ float bs[OUT_CH];
    for (int i = threadIdx.x; i < HID * OUT_CH; i += blockDim.x) Ws[i] = W2[i];
    for (int i = threadIdx.x; i < OUT_CH; i += blockDim.x) bs[i] = b2[i];
    __syncthreads();
    int n = blockIdx.x * blockDim.x + threadIdx.x;
    if (n >= N) return;
    float sn = dinv[n] * dinv[n];
    float v[HID];
#pragma unroll
    for (int q = 0; q < 4; ++q) {
        float4 hv = *(const float4*)(h + (size_t)n * HID + 4 * q);
        float4 av = *(const float4*)(a2 + (size_t)n * HID + 4 * q);
        v[4 * q + 0] = av.x + hv.x * sn;
        v[4 * q + 1] = av.y + hv.y * sn;
        v[4 * q + 2] = av.z + hv.z * sn;
        v[4 * q + 3] = av.w + hv.w * sn;
    }
    float pre[OUT_CH];
#pragma unroll
    for (int j = 0; j < OUT_CH; ++j) pre[j] = bs[j];
#pragma unroll
    for (int i = 0; i < HID; ++i) {
        float vi = v[i];
#pragma unroll
        for (int j = 0; j < OUT_CH; ++j) pre[j] += vi * Ws[i * OUT_CH + j];
    }
    float m = pre[0];
#pragma unroll
    for (int j = 1; j < OUT_CH; ++j) m = fmaxf(m, pre[j]);
    float s = 0.f;
#pragma unroll
    for (int j = 0; j < OUT_CH; ++j) s += expf(pre[j] - m);
    float lse = m + logf(s);
    float* o = out + (size_t)n * OUT_CH;
#pragma unroll
    for (int j = 0; j < OUT_CH; ++j) o[j] = pre[j] - lse;
}

extern "C" void kernel_launch(void* const* d_in, const int* in_sizes, int n_in,
                              void* d_out, int out_size, void* d_ws, size_t ws_size,
                              hipStream_t stream) {
    const float* x  = (const float*)d_in[0];
    const int*   ei = (const int*)d_in[1];      // [2, E] int32 (jax x64 disabled)
    const float* W1 = (const float*)d_in[2];
    const float* b1 = (const float*)d_in[3];
    const float* W2 = (const float*)d_in[4];
    const float* b2 = (const float*)d_in[5];
    float* out = (float*)d_out;

    const int* row = ei;
    const int* col = ei + N_EDGES;

    // workspace layout: [deg/dinv: N][a1: N*16][a2: N*16][h1: N*16]
    float* deg = (float*)d_ws;
    float* a1  = deg + N_NODES;
    float* a2  = a1 + (size_t)N_NODES * HID;
    float* h1  = a2 + (size_t)N_NODES * HID;

    // zero deg + a1 + a2 in one shot (contiguous)
    hipMemsetAsync(d_ws, 0, (size_t)(N_NODES + 2 * (size_t)N_NODES * HID) * sizeof(float), stream);

    const int B = 256;
    deg_kernel<<<(N_EDGES + B - 1) / B, B, 0, stream>>>(col, deg, N_EDGES);
    dinv_kernel<<<(N_NODES + B - 1) / B, B, 0, stream>>>(deg, N_NODES);
    gemm1_kernel<<<(N_NODES + B - 1) / B, B, 0, stream>>>(x, W1, h1, N_NODES);
    scatter16_kernel<<<(N_EDGES + B - 1) / B, B, 0, stream>>>(row, col, deg, h1, a1, N_EDGES);
    relu_kernel<<<(N_NODES + B - 1) / B, B, 0, stream>>>(h1, a1, deg, b1, N_NODES);
    scatter16_kernel<<<(N_EDGES + B - 1) / B, B, 0, stream>>>(row, col, deg, h1, a2, N_EDGES);
    final_kernel<<<(N_NODES + B - 1) / B, B, 0, stream>>>(a2, h1, deg, W2, b2, out, N_NODES);
}

// Round 3
// 775.299 us; speedup vs baseline: 7.2612x; 7.2612x over previous
//
#include <hip/hip_runtime.h>

#define N_NODES 100000
#define N_EDGES 3200000
#define IN_CH 256
#define HID 16
#define OUT_CH 40
#define CHUNK 256
#define NCHUNK ((N_NODES + CHUNK - 1) / CHUNK)   // 391

// ---------------- int in-degree: degi[col] += 1 ----------------
__global__ void count_kernel(const int* __restrict__ col, int* __restrict__ degi, int E) {
    int e = blockIdx.x * blockDim.x + threadIdx.x;
    if (e < E) atomicAdd(&degi[col[e]], 1);
}

// ---------------- dinv = rsqrt(degi + 1) ----------------
__global__ void dinv_kernel(const int* __restrict__ degi, float* __restrict__ dinv, int N) {
    int i = blockIdx.x * blockDim.x + threadIdx.x;
    if (i < N) dinv[i] = rsqrtf((float)degi[i] + 1.0f);
}

// ---------------- exclusive scan, 3-phase ----------------
__global__ void scan_chunk_kernel(const int* __restrict__ in, int* __restrict__ out,
                                  int* __restrict__ sums, int N) {
    __shared__ int buf[2][CHUNK];
    int t = threadIdx.x;
    int gid = blockIdx.x * CHUNK + t;
    int v = (gid < N) ? in[gid] : 0;
    int src = 0;
    buf[0][t] = v;
    __syncthreads();
    for (int off = 1; off < CHUNK; off <<= 1) {
        int val = buf[src][t];
        if (t >= off) val += buf[src][t - off];
        buf[src ^ 1][t] = val;
        src ^= 1;
        __syncthreads();
    }
    int inc = buf[src][t];
    if (gid < N) out[gid] = inc - v;            // exclusive
    if (t == CHUNK - 1) sums[blockIdx.x] = inc; // chunk total
}

__global__ void scan_sums_kernel(int* __restrict__ sums, int n) {
    __shared__ int buf[2][512];
    int t = threadIdx.x;
    int v = (t < n) ? sums[t] : 0;
    int src = 0;
    buf[0][t] = v;
    __syncthreads();
    for (int off = 1; off < 512; off <<= 1) {
        int val = buf[src][t];
        if (t >= off) val += buf[src][t - off];
        buf[src ^ 1][t] = val;
        src ^= 1;
        __syncthreads();
    }
    if (t < n) sums[t] = buf[src][t] - v;       // exclusive, in place
}

__global__ void add_base_kernel(int* __restrict__ offs, int* __restrict__ cursor,
                                const int* __restrict__ sums, int N) {
    int gid = blockIdx.x * CHUNK + threadIdx.x;
    if (gid < N) {
        int o = offs[gid] + sums[blockIdx.x];
        offs[gid] = o;
        cursor[gid] = o;
    }
}

// ---------------- CSR fill: csr_row[cursor[col]++] = row ----------------
__global__ void fill_kernel(const int* __restrict__ row, const int* __restrict__ col,
                            int* __restrict__ cursor, int* __restrict__ csr_row, int E) {
    int e = blockIdx.x * blockDim.x + threadIdx.x;
    if (e < E) {
        int p = atomicAdd(&cursor[col[e]], 1);
        csr_row[p] = row[e];
    }
}

// ---------------- g1 = (x @ W1) * dinv[r]   [N,256]@[256,16] ----------------
__global__ void gemm1_kernel(const float* __restrict__ x, const float* __restrict__ W1,
                             const float* __restrict__ dinv, float* __restrict__ g1, int N) {
    __shared__ float Ws[IN_CH * HID];   // 16 KB
    for (int i = threadIdx.x; i < IN_CH * HID; i += blockDim.x) Ws[i] = W1[i];
    __syncthreads();
    int r = blockIdx.x * blockDim.x + threadIdx.x;
    if (r >= N) return;
    float acc[HID];
#pragma unroll
    for (int j = 0; j < HID; ++j) acc[j] = 0.f;
    const float4* xr = (const float4*)(x + (size_t)r * IN_CH);
#pragma unroll 4
    for (int c = 0; c < IN_CH / 4; ++c) {
        float4 v = xr[c];
        const float* w = &Ws[c * 4 * HID];
#pragma unroll
        for (int j = 0; j < HID; ++j)
            acc[j] += v.x * w[j] + v.y * w[HID + j] + v.z * w[2 * HID + j] + v.w * w[3 * HID + j];
    }
    float d = dinv[r];
    float* o = g1 + (size_t)r * HID;
#pragma unroll
    for (int j = 0; j < HID; j += 4)
        *(float4*)(o + j) = make_float4(acc[j] * d, acc[j + 1] * d, acc[j + 2] * d, acc[j + 3] * d);
}

// ---------------- gather layer1: g2 = relu(dinv*(sum+g1_self)+b1)*dinv ----------------
// 16 lanes per node, lane = channel
__global__ void gather1_kernel(const int* __restrict__ offs, const int* __restrict__ degi,
                               const int* __restrict__ csr_row, const float* __restrict__ g1,
                               const float* __restrict__ dinv, const float* __restrict__ b1,
                               float* __restrict__ g2, int N) {
    int t = blockIdx.x * blockDim.x + threadIdx.x;
    int node = t >> 4, lane = t & 15;
    if (node >= N) return;
    int beg = offs[node];
    int end = beg + degi[node];
    float sum = g1[(size_t)node * HID + lane];          // self term (g = h*dinv)
    for (int i = beg; i < end; ++i) {
        int r = csr_row[i];
        sum += g1[(size_t)r * HID + lane];
    }
    float d = dinv[node];
    float h = fmaxf(fmaf(sum, d, b1[lane]), 0.f);
    g2[(size_t)node * HID + lane] = h * d;
}

// ---------------- gather layer2 + W2 + log_softmax ----------------
__global__ void gather2_kernel(const int* __restrict__ offs, const int* __restrict__ degi,
                               const int* __restrict__ csr_row, const float* __restrict__ g2,
                               const float* __restrict__ dinv, const float* __restrict__ W2,
                               const float* __restrict__ b2, float* __restrict__ out, int N) {
    __shared__ float Ws[HID * OUT_CH];  // 2.5 KB
    __shared__ float bs[OUT_CH];
    for (int i = threadIdx.x; i < HID * OUT_CH; i += blockDim.x) Ws[i] = W2[i];
    for (int i = threadIdx.x; i < OUT_CH; i += blockDim.x) bs[i] = b2[i];
    __syncthreads();
    int t = blockIdx.x * blockDim.x + threadIdx.x;
    int node = t >> 4, lane = t & 15;
    if (node >= N) return;
    int beg = offs[node];
    int end = beg + degi[node];
    float sum = g2[(size_t)node * HID + lane];
    for (int i = beg; i < end; ++i) {
        int r = csr_row[i];
        sum += g2[(size_t)r * HID + lane];
    }
    float z = sum * dinv[node];                         // aggregated pre-W2, 16-dim
    // z @ W2 + b2: lane j computes output cols j, j+16, and (j<8) j+32
    float p0 = bs[lane], p1 = bs[lane + 16];
    float p2 = (lane < 8) ? bs[lane + 32] : -1e30f;
#pragma unroll
    for (int i = 0; i < HID; ++i) {
        float zi = __shfl(z, i, 16);
        p0 = fmaf(zi, Ws[i * OUT_CH + lane], p0);
        p1 = fmaf(zi, Ws[i * OUT_CH + lane + 16], p1);
        if (lane < 8) p2 = fmaf(zi, Ws[i * OUT_CH + lane + 32], p2);
    }
    float m = fmaxf(fmaxf(p0, p1), p2);
#pragma unroll
    for (int off = 8; off; off >>= 1) m = fmaxf(m, __shfl_xor(m, off, 16));
    float s = expf(p0 - m) + expf(p1 - m) + ((lane < 8) ? expf(p2 - m) : 0.f);
#pragma unroll
    for (int off = 8; off; off >>= 1) s += __shfl_xor(s, off, 16);
    float lse = m + logf(s);
    float* o = out + (size_t)node * OUT_CH;
    o[lane] = p0 - lse;
    o[lane + 16] = p1 - lse;
    if (lane < 8) o[lane + 32] = p2 - lse;
}

extern "C" void kernel_launch(void* const* d_in, const int* in_sizes, int n_in,
                              void* d_out, int out_size, void* d_ws, size_t ws_size,
                              hipStream_t stream) {
    const float* x  = (const float*)d_in[0];
    const int*   ei = (const int*)d_in[1];      // [2, E] int32
    const float* W1 = (const float*)d_in[2];
    const float* b1 = (const float*)d_in[3];
    const float* W2 = (const float*)d_in[4];
    const float* b2 = (const float*)d_in[5];
    float* out = (float*)d_out;

    const int* row = ei;
    const int* col = ei + N_EDGES;

    // ws layout (all 4-byte): degi[N] offs[N] cursor[N] sums[512] csr_row[E] dinv[N] g1[N*16] g2[N*16]
    int*   degi    = (int*)d_ws;
    int*   offs    = degi + N_NODES;
    int*   cursor  = offs + N_NODES;
    int*   sums    = cursor + N_NODES;
    int*   csr_row = sums + 512;
    float* dinv    = (float*)(csr_row + N_EDGES);
    float* g1      = dinv + N_NODES;
    float* g2      = g1 + (size_t)N_NODES * HID;

    hipMemsetAsync(degi, 0, (size_t)N_NODES * sizeof(int), stream);

    const int B = 256;
    const int gE = (N_EDGES + B - 1) / B;       // 12500
    const int gN = (N_NODES + B - 1) / B;       // 391

    count_kernel<<<gE, B, 0, stream>>>(col, degi, N_EDGES);
    dinv_kernel<<<gN, B, 0, stream>>>(degi, dinv, N_NODES);
    scan_chunk_kernel<<<NCHUNK, CHUNK, 0, stream>>>(degi, offs, sums, N_NODES);
    scan_sums_kernel<<<1, 512, 0, stream>>>(sums, NCHUNK);
    add_base_kernel<<<NCHUNK, CHUNK, 0, stream>>>(offs, cursor, sums, N_NODES);
    fill_kernel<<<gE, B, 0, stream>>>(row, col, cursor, csr_row, N_EDGES);
    gemm1_kernel<<<gN, B, 0, stream>>>(x, W1, dinv, g1, N_NODES);
    gather1_kernel<<<(N_NODES * 16 + B - 1) / B, B, 0, stream>>>(offs, degi, csr_row, g1, dinv, b1, g2, N_NODES);
    gather2_kernel<<<(N_NODES * 16 + B - 1) / B, B, 0, stream>>>(offs, degi, csr_row, g2, dinv, W2, b2, out, N_NODES);
}

// Round 4
// 595.036 us; speedup vs baseline: 9.4610x; 1.3029x over previous
//
#include <hip/hip_runtime.h>

#define N_NODES 100000
#define N_EDGES 3200000
#define IN_CH 256
#define HID 16
#define OUT_CH 40
#define CHUNK 256
#define NCHUNK ((N_NODES + CHUNK - 1) / CHUNK)   // 391

// ---------------- in-degree histogram + per-edge rank capture ----------------
__global__ void count_kernel(const int* __restrict__ col, int* __restrict__ degi,
                             int* __restrict__ rank, int E) {
    int e = blockIdx.x * blockDim.x + threadIdx.x;
    if (e < E) rank[e] = atomicAdd(&degi[col[e]], 1);
}

// ---------------- dinv = rsqrt(degi + 1) ----------------
__global__ void dinv_kernel(const int* __restrict__ degi, float* __restrict__ dinv, int N) {
    int i = blockIdx.x * blockDim.x + threadIdx.x;
    if (i < N) dinv[i] = rsqrtf((float)degi[i] + 1.0f);
}

// ---------------- exclusive scan, 3-phase ----------------
__global__ void scan_chunk_kernel(const int* __restrict__ in, int* __restrict__ out,
                                  int* __restrict__ sums, int N) {
    __shared__ int buf[2][CHUNK];
    int t = threadIdx.x;
    int gid = blockIdx.x * CHUNK + t;
    int v = (gid < N) ? in[gid] : 0;
    int src = 0;
    buf[0][t] = v;
    __syncthreads();
    for (int off = 1; off < CHUNK; off <<= 1) {
        int val = buf[src][t];
        if (t >= off) val += buf[src][t - off];
        buf[src ^ 1][t] = val;
        src ^= 1;
        __syncthreads();
    }
    int inc = buf[src][t];
    if (gid < N) out[gid] = inc - v;            // exclusive
    if (t == CHUNK - 1) sums[blockIdx.x] = inc; // chunk total
}

__global__ void scan_sums_kernel(int* __restrict__ sums, int n) {
    __shared__ int buf[2][512];
    int t = threadIdx.x;
    int v = (t < n) ? sums[t] : 0;
    int src = 0;
    buf[0][t] = v;
    __syncthreads();
    for (int off = 1; off < 512; off <<= 1) {
        int val = buf[src][t];
        if (t >= off) val += buf[src][t - off];
        buf[src ^ 1][t] = val;
        src ^= 1;
        __syncthreads();
    }
    if (t < n) sums[t] = buf[src][t] - v;       // exclusive, in place
}

__global__ void add_base_kernel(int* __restrict__ offs, const int* __restrict__ sums, int N) {
    int gid = blockIdx.x * CHUNK + threadIdx.x;
    if (gid < N) offs[gid] += sums[blockIdx.x];
}

// ---------------- CSR fill, atomic-free: csr_row[offs[col]+rank] = row ----------------
__global__ void fill_kernel(const int* __restrict__ row, const int* __restrict__ col,
                            const int* __restrict__ offs, const int* __restrict__ rank,
                            int* __restrict__ csr_row, int E) {
    int e = blockIdx.x * blockDim.x + threadIdx.x;
    if (e < E) csr_row[offs[col[e]] + rank[e]] = row[e];
}

// ---------------- g1 = (x @ W1) * dinv[r]   [N,256]@[256,16] ----------------
__global__ void gemm1_kernel(const float* __restrict__ x, const float* __restrict__ W1,
                             const float* __restrict__ dinv, float* __restrict__ g1, int N) {
    __shared__ float Ws[IN_CH * HID];   // 16 KB
    for (int i = threadIdx.x; i < IN_CH * HID; i += blockDim.x) Ws[i] = W1[i];
    __syncthreads();
    int r = blockIdx.x * blockDim.x + threadIdx.x;
    if (r >= N) return;
    float acc[HID];
#pragma unroll
    for (int j = 0; j < HID; ++j) acc[j] = 0.f;
    const float4* xr = (const float4*)(x + (size_t)r * IN_CH);
#pragma unroll 4
    for (int c = 0; c < IN_CH / 4; ++c) {
        float4 v = xr[c];
        const float* w = &Ws[c * 4 * HID];
#pragma unroll
        for (int j = 0; j < HID; ++j)
            acc[j] += v.x * w[j] + v.y * w[HID + j] + v.z * w[2 * HID + j] + v.w * w[3 * HID + j];
    }
    float d = dinv[r];
    float* o = g1 + (size_t)r * HID;
#pragma unroll
    for (int j = 0; j < HID; j += 4)
        *(float4*)(o + j) = make_float4(acc[j] * d, acc[j + 1] * d, acc[j + 2] * d, acc[j + 3] * d);
}

// ---------------- gather layer1: g2 = relu(dinv*(sum+g1_self)+b1)*dinv ----------------
// 16 lanes per node, lane = channel
__global__ void gather1_kernel(const int* __restrict__ offs, const int* __restrict__ degi,
                               const int* __restrict__ csr_row, const float* __restrict__ g1,
                               const float* __restrict__ dinv, const float* __restrict__ b1,
                               float* __restrict__ g2, int N) {
    int t = blockIdx.x * blockDim.x + threadIdx.x;
    int node = t >> 4, lane = t & 15;
    if (node >= N) return;
    int beg = offs[node];
    int end = beg + degi[node];
    float sum = g1[(size_t)node * HID + lane];          // self term (g = h*dinv)
    for (int i = beg; i < end; ++i) {
        int r = csr_row[i];
        sum += g1[(size_t)r * HID + lane];
    }
    float d = dinv[node];
    float h = fmaxf(fmaf(sum, d, b1[lane]), 0.f);
    g2[(size_t)node * HID + lane] = h * d;
}

// ---------------- gather layer2 + W2 + log_softmax ----------------
__global__ void gather2_kernel(const int* __restrict__ offs, const int* __restrict__ degi,
                               const int* __restrict__ csr_row, const float* __restrict__ g2,
                               const float* __restrict__ dinv, const float* __restrict__ W2,
                               const float* __restrict__ b2, float* __restrict__ out, int N) {
    __shared__ float Ws[HID * OUT_CH];  // 2.5 KB
    __shared__ float bs[OUT_CH];
    for (int i = threadIdx.x; i < HID * OUT_CH; i += blockDim.x) Ws[i] = W2[i];
    for (int i = threadIdx.x; i < OUT_CH; i += blockDim.x) bs[i] = b2[i];
    __syncthreads();
    int t = blockIdx.x * blockDim.x + threadIdx.x;
    int node = t >> 4, lane = t & 15;
    if (node >= N) return;
    int beg = offs[node];
    int end = beg + degi[node];
    float sum = g2[(size_t)node * HID + lane];
    for (int i = beg; i < end; ++i) {
        int r = csr_row[i];
        sum += g2[(size_t)r * HID + lane];
    }
    float z = sum * dinv[node];                         // aggregated pre-W2, 16-dim
    // z @ W2 + b2: lane j computes output cols j, j+16, and (j<8) j+32
    float p0 = bs[lane], p1 = bs[lane + 16];
    float p2 = (lane < 8) ? bs[lane + 32] : -1e30f;
#pragma unroll
    for (int i = 0; i < HID; ++i) {
        float zi = __shfl(z, i, 16);
        p0 = fmaf(zi, Ws[i * OUT_CH + lane], p0);
        p1 = fmaf(zi, Ws[i * OUT_CH + lane + 16], p1);
        if (lane < 8) p2 = fmaf(zi, Ws[i * OUT_CH + lane + 32], p2);
    }
    float m = fmaxf(fmaxf(p0, p1), p2);
#pragma unroll
    for (int off = 8; off; off >>= 1) m = fmaxf(m, __shfl_xor(m, off, 16));
    float s = expf(p0 - m) + expf(p1 - m) + ((lane < 8) ? expf(p2 - m) : 0.f);
#pragma unroll
    for (int off = 8; off; off >>= 1) s += __shfl_xor(s, off, 16);
    float lse = m + logf(s);
    float* o = out + (size_t)node * OUT_CH;
    o[lane] = p0 - lse;
    o[lane + 16] = p1 - lse;
    if (lane < 8) o[lane + 32] = p2 - lse;
}

extern "C" void kernel_launch(void* const* d_in, const int* in_sizes, int n_in,
                              void* d_out, int out_size, void* d_ws, size_t ws_size,
                              hipStream_t stream) {
    const float* x  = (const float*)d_in[0];
    const int*   ei = (const int*)d_in[1];      // [2, E] int32
    const float* W1 = (const float*)d_in[2];
    const float* b1 = (const float*)d_in[3];
    const float* W2 = (const float*)d_in[4];
    const float* b2 = (const float*)d_in[5];
    float* out = (float*)d_out;

    const int* row = ei;
    const int* col = ei + N_EDGES;

    // ws layout (all 4-byte): degi[N] offs[N] sums[512] rank[E] csr_row[E] dinv[N] g1[N*16] g2[N*16]
    int*   degi    = (int*)d_ws;
    int*   offs    = degi + N_NODES;
    int*   sums    = offs + N_NODES;
    int*   rank    = sums + 512;
    int*   csr_row = rank + N_EDGES;
    float* dinv    = (float*)(csr_row + N_EDGES);
    float* g1      = dinv + N_NODES;
    float* g2      = g1 + (size_t)N_NODES * HID;

    hipMemsetAsync(degi, 0, (size_t)N_NODES * sizeof(int), stream);

    const int B = 256;
    const int gE = (N_EDGES + B - 1) / B;       // 12500
    const int gN = (N_NODES + B - 1) / B;       // 391

    count_kernel<<<gE, B, 0, stream>>>(col, degi, rank, N_EDGES);
    dinv_kernel<<<gN, B, 0, stream>>>(degi, dinv, N_NODES);
    scan_chunk_kernel<<<NCHUNK, CHUNK, 0, stream>>>(degi, offs, sums, N_NODES);
    scan_sums_kernel<<<1, 512, 0, stream>>>(sums, NCHUNK);
    add_base_kernel<<<NCHUNK, CHUNK, 0, stream>>>(offs, sums, N_NODES);
    fill_kernel<<<gE, B, 0, stream>>>(row, col, offs, rank, csr_row, N_EDGES);
    gemm1_kernel<<<gN, B, 0, stream>>>(x, W1, dinv, g1, N_NODES);
    gather1_kernel<<<(N_NODES * 16 + B - 1) / B, B, 0, stream>>>(offs, degi, csr_row, g1, dinv, b1, g2, N_NODES);
    gather2_kernel<<<(N_NODES * 16 + B - 1) / B, B, 0, stream>>>(offs, degi, csr_row, g2, dinv, W2, b2, out, N_NODES);
}

// Round 5
// 508.873 us; speedup vs baseline: 11.0629x; 1.1693x over previous
//
#include <hip/hip_runtime.h>

#define N_NODES 100000
#define N_EDGES 3200000
#define IN_CH 256
#define HID 16
#define OUT_CH 40
#define CHUNK 256
#define NCHUNK ((N_NODES + CHUNK - 1) / CHUNK)   // 391

// ---- bf16x2 pack/unpack (RNE) ----
__device__ inline unsigned pack_bf16x2(float a, float b) {
    unsigned ua = __builtin_bit_cast(unsigned, a);
    unsigned ub = __builtin_bit_cast(unsigned, b);
    ua = (ua + 0x7FFFu + ((ua >> 16) & 1u)) >> 16;
    ub = (ub + 0x7FFFu + ((ub >> 16) & 1u)) >> 16;
    return ua | (ub << 16);
}
__device__ inline float2 unpack_bf16x2(unsigned u) {
    float lo = __builtin_bit_cast(float, u << 16);
    float hi = __builtin_bit_cast(float, u & 0xFFFF0000u);
    return make_float2(lo, hi);
}

// ---------------- in-degree histogram + per-edge rank capture ----------------
__global__ void count_kernel(const int* __restrict__ col, int* __restrict__ degi,
                             int* __restrict__ rank, int E) {
    int e = blockIdx.x * blockDim.x + threadIdx.x;
    if (e < E) rank[e] = atomicAdd(&degi[col[e]], 1);
}

// ---------------- dinv = rsqrt(degi + 1) ----------------
__global__ void dinv_kernel(const int* __restrict__ degi, float* __restrict__ dinv, int N) {
    int i = blockIdx.x * blockDim.x + threadIdx.x;
    if (i < N) dinv[i] = rsqrtf((float)degi[i] + 1.0f);
}

// ---------------- exclusive scan, 3-phase ----------------
__global__ void scan_chunk_kernel(const int* __restrict__ in, int* __restrict__ out,
                                  int* __restrict__ sums, int N) {
    __shared__ int buf[2][CHUNK];
    int t = threadIdx.x;
    int gid = blockIdx.x * CHUNK + t;
    int v = (gid < N) ? in[gid] : 0;
    int src = 0;
    buf[0][t] = v;
    __syncthreads();
    for (int off = 1; off < CHUNK; off <<= 1) {
        int val = buf[src][t];
        if (t >= off) val += buf[src][t - off];
        buf[src ^ 1][t] = val;
        src ^= 1;
        __syncthreads();
    }
    int inc = buf[src][t];
    if (gid < N) out[gid] = inc - v;            // exclusive
    if (t == CHUNK - 1) sums[blockIdx.x] = inc; // chunk total
}

__global__ void scan_sums_kernel(int* __restrict__ sums, int n) {
    __shared__ int buf[2][512];
    int t = threadIdx.x;
    int v = (t < n) ? sums[t] : 0;
    int src = 0;
    buf[0][t] = v;
    __syncthreads();
    for (int off = 1; off < 512; off <<= 1) {
        int val = buf[src][t];
        if (t >= off) val += buf[src][t - off];
        buf[src ^ 1][t] = val;
        src ^= 1;
        __syncthreads();
    }
    if (t < n) sums[t] = buf[src][t] - v;       // exclusive, in place
}

__global__ void add_base_kernel(int* __restrict__ offs, const int* __restrict__ sums, int N) {
    int gid = blockIdx.x * CHUNK + threadIdx.x;
    if (gid < N) offs[gid] += sums[blockIdx.x];
}

// ---------------- CSR fill, atomic-free: csr_row[offs[col]+rank] = row ----------------
__global__ void fill_kernel(const int* __restrict__ row, const int* __restrict__ col,
                            const int* __restrict__ offs, const int* __restrict__ rank,
                            int* __restrict__ csr_row, int E) {
    int e = blockIdx.x * blockDim.x + threadIdx.x;
    if (e < E) csr_row[offs[col[e]] + rank[e]] = row[e];
}

// ---------------- g1 = (x @ W1) * dinv[r], stored bf16x2[N*8] ----------------
__global__ void gemm1_kernel(const float* __restrict__ x, const float* __restrict__ W1,
                             const float* __restrict__ dinv, unsigned* __restrict__ g1, int N) {
    __shared__ float Ws[IN_CH * HID];   // 16 KB
    for (int i = threadIdx.x; i < IN_CH * HID; i += blockDim.x) Ws[i] = W1[i];
    __syncthreads();
    int r = blockIdx.x * blockDim.x + threadIdx.x;
    if (r >= N) return;
    float acc[HID];
#pragma unroll
    for (int j = 0; j < HID; ++j) acc[j] = 0.f;
    const float4* xr = (const float4*)(x + (size_t)r * IN_CH);
#pragma unroll 4
    for (int c = 0; c < IN_CH / 4; ++c) {
        float4 v = xr[c];
        const float* w = &Ws[c * 4 * HID];
#pragma unroll
        for (int j = 0; j < HID; ++j)
            acc[j] += v.x * w[j] + v.y * w[HID + j] + v.z * w[2 * HID + j] + v.w * w[3 * HID + j];
    }
    float d = dinv[r];
    uint4 o0, o1;
    o0.x = pack_bf16x2(acc[0] * d, acc[1] * d);
    o0.y = pack_bf16x2(acc[2] * d, acc[3] * d);
    o0.z = pack_bf16x2(acc[4] * d, acc[5] * d);
    o0.w = pack_bf16x2(acc[6] * d, acc[7] * d);
    o1.x = pack_bf16x2(acc[8] * d, acc[9] * d);
    o1.y = pack_bf16x2(acc[10] * d, acc[11] * d);
    o1.z = pack_bf16x2(acc[12] * d, acc[13] * d);
    o1.w = pack_bf16x2(acc[14] * d, acc[15] * d);
    uint4* o = (uint4*)(g1 + (size_t)r * 8);
    o[0] = o0;
    o[1] = o1;
}

// ---------------- gather layer1: g2 = relu(dinv*(sum+self)+b1)*dinv, bf16 ----------------
// 8 lanes per node; lane holds channels 2l, 2l+1
__global__ void gather1_kernel(const int* __restrict__ offs, const int* __restrict__ degi,
                               const int* __restrict__ csr_row, const unsigned* __restrict__ g1,
                               const float* __restrict__ dinv, const float* __restrict__ b1,
                               unsigned* __restrict__ g2, int N) {
    int t = blockIdx.x * blockDim.x + threadIdx.x;
    int node = t >> 3, lane = t & 7;
    if (node >= N) return;
    int beg = offs[node];
    int end = beg + degi[node];
    float2 self = unpack_bf16x2(g1[(size_t)node * 8 + lane]);
    float s0 = self.x, s1 = self.y;
    for (int i = beg; i < end; ++i) {
        int r = csr_row[i];
        float2 v = unpack_bf16x2(g1[(size_t)r * 8 + lane]);
        s0 += v.x;
        s1 += v.y;
    }
    float d = dinv[node];
    float h0 = fmaxf(fmaf(s0, d, b1[2 * lane]), 0.f);
    float h1 = fmaxf(fmaf(s1, d, b1[2 * lane + 1]), 0.f);
    g2[(size_t)node * 8 + lane] = pack_bf16x2(h0 * d, h1 * d);
}

// ---------------- gather layer2 + W2 + log_softmax ----------------
// 8 lanes per node; lane l computes output cols l, l+8, l+16, l+24, l+32
__global__ void gather2_kernel(const int* __restrict__ offs, const int* __restrict__ degi,
                               const int* __restrict__ csr_row, const unsigned* __restrict__ g2,
                               const float* __restrict__ dinv, const float* __restrict__ W2,
                               const float* __restrict__ b2, float* __restrict__ out, int N) {
    __shared__ float Ws[HID * OUT_CH];  // 2.5 KB
    __shared__ float bs[OUT_CH];
    for (int i = threadIdx.x; i < HID * OUT_CH; i += blockDim.x) Ws[i] = W2[i];
    for (int i = threadIdx.x; i < OUT_CH; i += blockDim.x) bs[i] = b2[i];
    __syncthreads();
    int t = blockIdx.x * blockDim.x + threadIdx.x;
    int node = t >> 3, lane = t & 7;
    if (node >= N) return;
    int beg = offs[node];
    int end = beg + degi[node];
    float2 self = unpack_bf16x2(g2[(size_t)node * 8 + lane]);
    float s0 = self.x, s1 = self.y;
    for (int i = beg; i < end; ++i) {
        int r = csr_row[i];
        float2 v = unpack_bf16x2(g2[(size_t)r * 8 + lane]);
        s0 += v.x;
        s1 += v.y;
    }
    float d = dinv[node];
    float2 zv = make_float2(s0 * d, s1 * d);            // channels 2l, 2l+1
    float p[5];
#pragma unroll
    for (int k = 0; k < 5; ++k) p[k] = bs[lane + 8 * k];
#pragma unroll
    for (int i = 0; i < HID; ++i) {
        float zi = __shfl((i & 1) ? zv.y : zv.x, i >> 1, 8);
#pragma unroll
        for (int k = 0; k < 5; ++k) p[k] = fmaf(zi, Ws[i * OUT_CH + lane + 8 * k], p[k]);
    }
    float m = p[0];
#pragma unroll
    for (int k = 1; k < 5; ++k) m = fmaxf(m, p[k]);
#pragma unroll
    for (int off = 4; off; off >>= 1) m = fmaxf(m, __shfl_xor(m, off, 8));
    float s = 0.f;
#pragma unroll
    for (int k = 0; k < 5; ++k) s += expf(p[k] - m);
#pragma unroll
    for (int off = 4; off; off >>= 1) s += __shfl_xor(s, off, 8);
    float lse = m + logf(s);
    float* o = out + (size_t)node * OUT_CH;
#pragma unroll
    for (int k = 0; k < 5; ++k) o[lane + 8 * k] = p[k] - lse;
}

extern "C" void kernel_launch(void* const* d_in, const int* in_sizes, int n_in,
                              void* d_out, int out_size, void* d_ws, size_t ws_size,
                              hipStream_t stream) {
    const float* x  = (const float*)d_in[0];
    const int*   ei = (const int*)d_in[1];      // [2, E] int32
    const float* W1 = (const float*)d_in[2];
    const float* b1 = (const float*)d_in[3];
    const float* W2 = (const float*)d_in[4];
    const float* b2 = (const float*)d_in[5];
    float* out = (float*)d_out;

    const int* row = ei;
    const int* col = ei + N_EDGES;

    // ws layout (4-byte units): degi[N] offs[N] sums[512] rank[E] csr_row[E] dinv[N] g1[N*8] g2[N*8]
    int*      degi    = (int*)d_ws;
    int*      offs    = degi + N_NODES;
    int*      sums    = offs + N_NODES;
    int*      rank    = sums + 512;
    int*      csr_row = rank + N_EDGES;
    float*    dinv    = (float*)(csr_row + N_EDGES);
    unsigned* g1      = (unsigned*)(dinv + N_NODES);
    unsigned* g2      = g1 + (size_t)N_NODES * 8;

    hipMemsetAsync(degi, 0, (size_t)N_NODES * sizeof(int), stream);

    const int B = 256;
    const int gE = (N_EDGES + B - 1) / B;       // 12500
    const int gN = (N_NODES + B - 1) / B;       // 391
    const int g8 = (N_NODES * 8 + B - 1) / B;   // 3125

    count_kernel<<<gE, B, 0, stream>>>(col, degi, rank, N_EDGES);
    dinv_kernel<<<gN, B, 0, stream>>>(degi, dinv, N_NODES);
    scan_chunk_kernel<<<NCHUNK, CHUNK, 0, stream>>>(degi, offs, sums, N_NODES);
    scan_sums_kernel<<<1, 512, 0, stream>>>(sums, NCHUNK);
    add_base_kernel<<<NCHUNK, CHUNK, 0, stream>>>(offs, sums, N_NODES);
    fill_kernel<<<gE, B, 0, stream>>>(row, col, offs, rank, csr_row, N_EDGES);
    gemm1_kernel<<<gN, B, 0, stream>>>(x, W1, dinv, g1, N_NODES);
    gather1_kernel<<<g8, B, 0, stream>>>(offs, degi, csr_row, g1, dinv, b1, g2, N_NODES);
    gather2_kernel<<<g8, B, 0, stream>>>(offs, degi, csr_row, g2, dinv, W2, b2, out, N_NODES);
}

// Round 6
// 506.350 us; speedup vs baseline: 11.1180x; 1.0050x over previous
//
#include <hip/hip_runtime.h>

#define N_NODES 100000
#define N_EDGES 3200000
#define IN_CH 256
#define HID 16
#define OUT_CH 40
#define CHUNK 256
#define NCHUNK ((N_NODES + CHUNK - 1) / CHUNK)   // 391

#define GEMM_BLOCKS 391          // ceil(100000/256)
#define EDGE_BLOCKS 3125         // 3125*256*4 == 3,200,000 exactly
#define EDGE_STRIDE (EDGE_BLOCKS * 256)

// ---- bf16x2 pack/unpack (RNE) ----
__device__ inline unsigned pack_bf16x2(float a, float b) {
    unsigned ua = __builtin_bit_cast(unsigned, a);
    unsigned ub = __builtin_bit_cast(unsigned, b);
    ua = (ua + 0x7FFFu + ((ua >> 16) & 1u)) >> 16;
    ub = (ub + 0x7FFFu + ((ub >> 16) & 1u)) >> 16;
    return ua | (ub << 16);
}
__device__ inline float2 unpack_bf16x2(unsigned u) {
    float lo = __builtin_bit_cast(float, u << 16);
    float hi = __builtin_bit_cast(float, u & 0xFFFF0000u);
    return make_float2(lo, hi);
}

// ---------------- fused: blocks [0,GEMM_BLOCKS) do g1 = bf16(x@W1) (unscaled);
//                  blocks [GEMM_BLOCKS, +EDGE_BLOCKS) do histogram+rank ----------------
__global__ __launch_bounds__(256, 8)
void fused_count_gemm_kernel(const float* __restrict__ x, const float* __restrict__ W1,
                             unsigned* __restrict__ g1,
                             const int* __restrict__ col, int* __restrict__ degi,
                             int* __restrict__ rank) {
    __shared__ float Ws[IN_CH * HID];   // 16 KB (allocated for all blocks; LDS not the occupancy limiter)
    int bid = blockIdx.x;
    if (bid < GEMM_BLOCKS) {
        for (int i = threadIdx.x; i < IN_CH * HID; i += blockDim.x) Ws[i] = W1[i];
        __syncthreads();
        int r = bid * 256 + threadIdx.x;
        if (r >= N_NODES) return;
        float acc[HID];
#pragma unroll
        for (int j = 0; j < HID; ++j) acc[j] = 0.f;
        const float4* xr = (const float4*)(x + (size_t)r * IN_CH);
#pragma unroll 4
        for (int c = 0; c < IN_CH / 4; ++c) {
            float4 v = xr[c];
            const float* w = &Ws[c * 4 * HID];
#pragma unroll
            for (int j = 0; j < HID; ++j)
                acc[j] += v.x * w[j] + v.y * w[HID + j] + v.z * w[2 * HID + j] + v.w * w[3 * HID + j];
        }
        uint4 o0, o1;
        o0.x = pack_bf16x2(acc[0], acc[1]);
        o0.y = pack_bf16x2(acc[2], acc[3]);
        o0.z = pack_bf16x2(acc[4], acc[5]);
        o0.w = pack_bf16x2(acc[6], acc[7]);
        o1.x = pack_bf16x2(acc[8], acc[9]);
        o1.y = pack_bf16x2(acc[10], acc[11]);
        o1.z = pack_bf16x2(acc[12], acc[13]);
        o1.w = pack_bf16x2(acc[14], acc[15]);
        uint4* o = (uint4*)(g1 + (size_t)r * 8);
        o[0] = o0;
        o[1] = o1;
    } else {
        int e0 = (bid - GEMM_BLOCKS) * 256 + threadIdx.x;
#pragma unroll
        for (int k = 0; k < 4; ++k) {
            int e = e0 + k * EDGE_STRIDE;
            rank[e] = atomicAdd(&degi[col[e]], 1);
        }
    }
}

// ---------------- exclusive scan over degi (+ dinv side-product) ----------------
__global__ void scan_chunk_kernel(const int* __restrict__ in, int* __restrict__ out,
                                  int* __restrict__ sums, float* __restrict__ dinv, int N) {
    __shared__ int buf[2][CHUNK];
    int t = threadIdx.x;
    int gid = blockIdx.x * CHUNK + t;
    int v = (gid < N) ? in[gid] : 0;
    if (gid < N) dinv[gid] = rsqrtf((float)v + 1.0f);
    int src = 0;
    buf[0][t] = v;
    __syncthreads();
    for (int off = 1; off < CHUNK; off <<= 1) {
        int val = buf[src][t];
        if (t >= off) val += buf[src][t - off];
        buf[src ^ 1][t] = val;
        src ^= 1;
        __syncthreads();
    }
    int inc = buf[src][t];
    if (gid < N) out[gid] = inc - v;            // exclusive
    if (t == CHUNK - 1) sums[blockIdx.x] = inc; // chunk total
}

__global__ void scan_sums_kernel(int* __restrict__ sums, int n) {
    __shared__ int buf[2][512];
    int t = threadIdx.x;
    int v = (t < n) ? sums[t] : 0;
    int src = 0;
    buf[0][t] = v;
    __syncthreads();
    for (int off = 1; off < 512; off <<= 1) {
        int val = buf[src][t];
        if (t >= off) val += buf[src][t - off];
        buf[src ^ 1][t] = val;
        src ^= 1;
        __syncthreads();
    }
    if (t < n) sums[t] = buf[src][t] - v;       // exclusive, in place
}

__global__ void add_base_kernel(int* __restrict__ offs, const int* __restrict__ sums, int N) {
    int gid = blockIdx.x * CHUNK + threadIdx.x;
    if (gid < N) offs[gid] += sums[blockIdx.x];
}

// ---------------- CSR fill, atomic-free, 4 edges/thread ----------------
__global__ void fill_kernel(const int* __restrict__ row, const int* __restrict__ col,
                            const int* __restrict__ offs, const int* __restrict__ rank,
                            int* __restrict__ csr_row) {
    int e0 = blockIdx.x * blockDim.x + threadIdx.x;
#pragma unroll
    for (int k = 0; k < 4; ++k) {
        int e = e0 + k * EDGE_STRIDE;
        csr_row[offs[col[e]] + rank[e]] = row[e];
    }
}

// ---------------- gather layer1: per-edge dinv[r] fold; g2 = relu(dinv*(sum)+b1)*dinv ----------------
// 8 lanes per node; lane holds channels 2l, 2l+1
__global__ void gather1_kernel(const int* __restrict__ offs, const int* __restrict__ degi,
                               const int* __restrict__ csr_row, const unsigned* __restrict__ g1,
                               const float* __restrict__ dinv, const float* __restrict__ b1,
                               unsigned* __restrict__ g2, int N) {
    int t = blockIdx.x * blockDim.x + threadIdx.x;
    int node = t >> 3, lane = t & 7;
    if (node >= N) return;
    int beg = offs[node];
    int end = beg + degi[node];
    float d = dinv[node];
    float2 self = unpack_bf16x2(g1[(size_t)node * 8 + lane]);
    float s0 = self.x * d, s1 = self.y * d;     // self term: h1[c]*dinv[c]
    for (int i = beg; i < end; ++i) {
        int r = csr_row[i];
        float dv = dinv[r];
        float2 v = unpack_bf16x2(g1[(size_t)r * 8 + lane]);
        s0 = fmaf(v.x, dv, s0);
        s1 = fmaf(v.y, dv, s1);
    }
    float h0 = fmaxf(fmaf(s0, d, b1[2 * lane]), 0.f);
    float h1 = fmaxf(fmaf(s1, d, b1[2 * lane + 1]), 0.f);
    g2[(size_t)node * 8 + lane] = pack_bf16x2(h0 * d, h1 * d);   // fold dinv for layer 2
}

// ---------------- gather layer2 + W2 + log_softmax ----------------
// 8 lanes per node; lane l computes output cols l, l+8, l+16, l+24, l+32
__global__ void gather2_kernel(const int* __restrict__ offs, const int* __restrict__ degi,
                               const int* __restrict__ csr_row, const unsigned* __restrict__ g2,
                               const float* __restrict__ dinv, const float* __restrict__ W2,
                               const float* __restrict__ b2, float* __restrict__ out, int N) {
    __shared__ float Ws[HID * OUT_CH];  // 2.5 KB
    __shared__ float bs[OUT_CH];
    for (int i = threadIdx.x; i < HID * OUT_CH; i += blockDim.x) Ws[i] = W2[i];
    for (int i = threadIdx.x; i < OUT_CH; i += blockDim.x) bs[i] = b2[i];
    __syncthreads();
    int t = blockIdx.x * blockDim.x + threadIdx.x;
    int node = t >> 3, lane = t & 7;
    if (node >= N) return;
    int beg = offs[node];
    int end = beg + degi[node];
    float2 self = unpack_bf16x2(g2[(size_t)node * 8 + lane]);
    float s0 = self.x, s1 = self.y;
    for (int i = beg; i < end; ++i) {
        int r = csr_row[i];
        float2 v = unpack_bf16x2(g2[(size_t)r * 8 + lane]);
        s0 += v.x;
        s1 += v.y;
    }
    float d = dinv[node];
    float2 zv = make_float2(s0 * d, s1 * d);            // channels 2l, 2l+1
    float p[5];
#pragma unroll
    for (int k = 0; k < 5; ++k) p[k] = bs[lane + 8 * k];
#pragma unroll
    for (int i = 0; i < HID; ++i) {
        float zi = __shfl((i & 1) ? zv.y : zv.x, i >> 1, 8);
#pragma unroll
        for (int k = 0; k < 5; ++k) p[k] = fmaf(zi, Ws[i * OUT_CH + lane + 8 * k], p[k]);
    }
    float m = p[0];
#pragma unroll
    for (int k = 1; k < 5; ++k) m = fmaxf(m, p[k]);
#pragma unroll
    for (int off = 4; off; off >>= 1) m = fmaxf(m, __shfl_xor(m, off, 8));
    float s = 0.f;
#pragma unroll
    for (int k = 0; k < 5; ++k) s += expf(p[k] - m);
#pragma unroll
    for (int off = 4; off; off >>= 1) s += __shfl_xor(s, off, 8);
    float lse = m + logf(s);
    float* o = out + (size_t)node * OUT_CH;
#pragma unroll
    for (int k = 0; k < 5; ++k) o[lane + 8 * k] = p[k] - lse;
}

extern "C" void kernel_launch(void* const* d_in, const int* in_sizes, int n_in,
                              void* d_out, int out_size, void* d_ws, size_t ws_size,
                              hipStream_t stream) {
    const float* x  = (const float*)d_in[0];
    const int*   ei = (const int*)d_in[1];      // [2, E] int32
    const float* W1 = (const float*)d_in[2];
    const float* b1 = (const float*)d_in[3];
    const float* W2 = (const float*)d_in[4];
    const float* b2 = (const float*)d_in[5];
    float* out = (float*)d_out;

    const int* row = ei;
    const int* col = ei + N_EDGES;

    // ws layout (4-byte units): degi[N] offs[N] sums[512] rank[E] csr_row[E] dinv[N] g1[N*8] g2[N*8]
    int*      degi    = (int*)d_ws;
    int*      offs    = degi + N_NODES;
    int*      sums    = offs + N_NODES;
    int*      rank    = sums + 512;
    int*      csr_row = rank + N_EDGES;
    float*    dinv    = (float*)(csr_row + N_EDGES);
    unsigned* g1      = (unsigned*)(dinv + N_NODES);
    unsigned* g2      = g1 + (size_t)N_NODES * 8;

    hipMemsetAsync(degi, 0, (size_t)N_NODES * sizeof(int), stream);

    const int B = 256;
    const int g8 = (N_NODES * 8 + B - 1) / B;   // 3125

    fused_count_gemm_kernel<<<GEMM_BLOCKS + EDGE_BLOCKS, B, 0, stream>>>(x, W1, g1, col, degi, rank);
    scan_chunk_kernel<<<NCHUNK, CHUNK, 0, stream>>>(degi, offs, sums, dinv, N_NODES);
    scan_sums_kernel<<<1, 512, 0, stream>>>(sums, NCHUNK);
    add_base_kernel<<<NCHUNK, CHUNK, 0, stream>>>(offs, sums, N_NODES);
    fill_kernel<<<EDGE_BLOCKS, B, 0, stream>>>(row, col, offs, rank, csr_row);
    gather1_kernel<<<g8, B, 0, stream>>>(offs, degi, csr_row, g1, dinv, b1, g2, N_NODES);
    gather2_kernel<<<g8, B, 0, stream>>>(offs, degi, csr_row, g2, dinv, W2, b2, out, N_NODES);
}

// Round 7
// 473.124 us; speedup vs baseline: 11.8988x; 1.0702x over previous
//
#include <hip/hip_runtime.h>

#define N_NODES 100000
#define N_EDGES 3200000
#define IN_CH 256
#define HID 16
#define OUT_CH 40
#define CHUNK 256
#define NCHUNK ((N_NODES + CHUNK - 1) / CHUNK)   // 391

#define GEMM_BLOCKS 391          // ceil(100000/256)
#define EDGE_BLOCKS 3125         // 3125*256*4 == 3,200,000 exactly
#define EDGE_STRIDE (EDGE_BLOCKS * 256)

// ---- bf16x2 pack/unpack (RNE) ----
__device__ inline unsigned pack_bf16x2(float a, float b) {
    unsigned ua = __builtin_bit_cast(unsigned, a);
    unsigned ub = __builtin_bit_cast(unsigned, b);
    ua = (ua + 0x7FFFu + ((ua >> 16) & 1u)) >> 16;
    ub = (ub + 0x7FFFu + ((ub >> 16) & 1u)) >> 16;
    return ua | (ub << 16);
}
__device__ inline float2 unpack_bf16x2(unsigned u) {
    float lo = __builtin_bit_cast(float, u << 16);
    float hi = __builtin_bit_cast(float, u & 0xFFFF0000u);
    return make_float2(lo, hi);
}

// ---------------- fused: blocks [0,GEMM_BLOCKS) do g1 = bf16(x@W1) (unscaled);
//                  blocks [GEMM_BLOCKS, +EDGE_BLOCKS) do histogram+rank ----------------
__global__ __launch_bounds__(256, 8)
void fused_count_gemm_kernel(const float* __restrict__ x, const float* __restrict__ W1,
                             unsigned* __restrict__ g1,
                             const int* __restrict__ col, int* __restrict__ degi,
                             int* __restrict__ rank) {
    __shared__ float Ws[IN_CH * HID];   // 16 KB
    int bid = blockIdx.x;
    if (bid < GEMM_BLOCKS) {
        for (int i = threadIdx.x; i < IN_CH * HID; i += blockDim.x) Ws[i] = W1[i];
        __syncthreads();
        int r = bid * 256 + threadIdx.x;
        if (r >= N_NODES) return;
        float acc[HID];
#pragma unroll
        for (int j = 0; j < HID; ++j) acc[j] = 0.f;
        const float4* xr = (const float4*)(x + (size_t)r * IN_CH);
#pragma unroll 4
        for (int c = 0; c < IN_CH / 4; ++c) {
            float4 v = xr[c];
            const float* w = &Ws[c * 4 * HID];
#pragma unroll
            for (int j = 0; j < HID; ++j)
                acc[j] += v.x * w[j] + v.y * w[HID + j] + v.z * w[2 * HID + j] + v.w * w[3 * HID + j];
        }
        uint4 o0, o1;
        o0.x = pack_bf16x2(acc[0], acc[1]);
        o0.y = pack_bf16x2(acc[2], acc[3]);
        o0.z = pack_bf16x2(acc[4], acc[5]);
        o0.w = pack_bf16x2(acc[6], acc[7]);
        o1.x = pack_bf16x2(acc[8], acc[9]);
        o1.y = pack_bf16x2(acc[10], acc[11]);
        o1.z = pack_bf16x2(acc[12], acc[13]);
        o1.w = pack_bf16x2(acc[14], acc[15]);
        uint4* o = (uint4*)(g1 + (size_t)r * 8);
        o[0] = o0;
        o[1] = o1;
    } else {
        int e0 = (bid - GEMM_BLOCKS) * 256 + threadIdx.x;
#pragma unroll
        for (int k = 0; k < 4; ++k) {
            int e = e0 + k * EDGE_STRIDE;
            rank[e] = atomicAdd(&degi[col[e]], 1);
        }
    }
}

// ---------------- exclusive scan over PADDED degi + dinv side-product ----------------
// offs are multiples of 4 -> every node's CSR segment starts 16B-aligned.
__global__ void scan_chunk_kernel(const int* __restrict__ in, int* __restrict__ out,
                                  int* __restrict__ sums, float* __restrict__ dinv, int N) {
    __shared__ int buf[2][CHUNK];
    int t = threadIdx.x;
    int gid = blockIdx.x * CHUNK + t;
    int d = (gid < N) ? in[gid] : 0;
    if (gid < N) dinv[gid] = rsqrtf((float)d + 1.0f);
    int v = (d + 3) & ~3;                       // padded degree
    int src = 0;
    buf[0][t] = v;
    __syncthreads();
    for (int off = 1; off < CHUNK; off <<= 1) {
        int val = buf[src][t];
        if (t >= off) val += buf[src][t - off];
        buf[src ^ 1][t] = val;
        src ^= 1;
        __syncthreads();
    }
    int inc = buf[src][t];
    if (gid < N) out[gid] = inc - v;            // exclusive
    if (t == CHUNK - 1) sums[blockIdx.x] = inc; // chunk total
}

__global__ void scan_sums_kernel(int* __restrict__ sums, int n) {
    __shared__ int buf[2][512];
    int t = threadIdx.x;
    int v = (t < n) ? sums[t] : 0;
    int src = 0;
    buf[0][t] = v;
    __syncthreads();
    for (int off = 1; off < 512; off <<= 1) {
        int val = buf[src][t];
        if (t >= off) val += buf[src][t - off];
        buf[src ^ 1][t] = val;
        src ^= 1;
        __syncthreads();
    }
    if (t < n) sums[t] = buf[src][t] - v;       // exclusive, in place
}

__global__ void add_base_kernel(int* __restrict__ offs, const int* __restrict__ sums, int N) {
    int gid = blockIdx.x * CHUNK + threadIdx.x;
    if (gid < N) offs[gid] += sums[blockIdx.x];
}

// ---------------- CSR fill, atomic-free, 4 edges/thread ----------------
__global__ void fill_kernel(const int* __restrict__ row, const int* __restrict__ col,
                            const int* __restrict__ offs, const int* __restrict__ rank,
                            int* __restrict__ csr_row) {
    int e0 = blockIdx.x * blockDim.x + threadIdx.x;
#pragma unroll
    for (int k = 0; k < 4; ++k) {
        int e = e0 + k * EDGE_STRIDE;
        csr_row[offs[col[e]] + rank[e]] = row[e];
    }
}

// ---------------- gather layer1: unroll-4 pipelined; g2 = relu(dinv*sum+b1)*dinv ----------------
// 8 lanes per node; lane holds channels 2l, 2l+1
__global__ void gather1_kernel(const int* __restrict__ offs, const int* __restrict__ degi,
                               const int* __restrict__ csr_row, const unsigned* __restrict__ g1,
                               const float* __restrict__ dinv, const float* __restrict__ b1,
                               unsigned* __restrict__ g2, int N) {
    int t = blockIdx.x * blockDim.x + threadIdx.x;
    int node = t >> 3, lane = t & 7;
    if (node >= N) return;
    int beg = offs[node];                       // 16B-aligned (padded scan)
    int deg = degi[node];
    float d = dinv[node];
    float2 self = unpack_bf16x2(g1[(size_t)node * 8 + lane]);
    float s0 = self.x * d, s1 = self.y * d;     // self term: h1[c]*dinv[c]
    int nq = deg >> 2;
    const int4* q = (const int4*)(csr_row + beg);
    for (int i = 0; i < nq; ++i) {
        int4 r4 = q[i];
        // 8 independent loads in flight before any use
        unsigned u0 = g1[(size_t)r4.x * 8 + lane];
        unsigned u1 = g1[(size_t)r4.y * 8 + lane];
        unsigned u2 = g1[(size_t)r4.z * 8 + lane];
        unsigned u3 = g1[(size_t)r4.w * 8 + lane];
        float d0 = dinv[r4.x], d1 = dinv[r4.y], d2 = dinv[r4.z], d3 = dinv[r4.w];
        float2 v0 = unpack_bf16x2(u0), v1 = unpack_bf16x2(u1);
        float2 v2 = unpack_bf16x2(u2), v3 = unpack_bf16x2(u3);
        s0 = fmaf(v0.x, d0, fmaf(v1.x, d1, fmaf(v2.x, d2, fmaf(v3.x, d3, s0))));
        s1 = fmaf(v0.y, d0, fmaf(v1.y, d1, fmaf(v2.y, d2, fmaf(v3.y, d3, s1))));
    }
    for (int i = beg + (nq << 2); i < beg + deg; ++i) {
        int r = csr_row[i];
        float dv = dinv[r];
        float2 v = unpack_bf16x2(g1[(size_t)r * 8 + lane]);
        s0 = fmaf(v.x, dv, s0);
        s1 = fmaf(v.y, dv, s1);
    }
    float h0 = fmaxf(fmaf(s0, d, b1[2 * lane]), 0.f);
    float h1 = fmaxf(fmaf(s1, d, b1[2 * lane + 1]), 0.f);
    g2[(size_t)node * 8 + lane] = pack_bf16x2(h0 * d, h1 * d);   // fold dinv for layer 2
}

// ---------------- gather layer2 + W2 + log_softmax, unroll-4 pipelined ----------------
// 8 lanes per node; lane l computes output cols l, l+8, l+16, l+24, l+32
__global__ void gather2_kernel(const int* __restrict__ offs, const int* __restrict__ degi,
                               const int* __restrict__ csr_row, const unsigned* __restrict__ g2,
                               const float* __restrict__ dinv, const float* __restrict__ W2,
                               const float* __restrict__ b2, float* __restrict__ out, int N) {
    __shared__ float Ws[HID * OUT_CH];  // 2.5 KB
    __shared__ float bs[OUT_CH];
    for (int i = threadIdx.x; i < HID * OUT_CH; i += blockDim.x) Ws[i] = W2[i];
    for (int i = threadIdx.x; i < OUT_CH; i += blockDim.x) bs[i] = b2[i];
    __syncthreads();
    int t = blockIdx.x * blockDim.x + threadIdx.x;
    int node = t >> 3, lane = t & 7;
    if (node >= N) return;
    int beg = offs[node];
    int deg = degi[node];
    float2 self = unpack_bf16x2(g2[(size_t)node * 8 + lane]);
    float s0 = self.x, s1 = self.y;
    int nq = deg >> 2;
    const int4* q = (const int4*)(csr_row + beg);
    for (int i = 0; i < nq; ++i) {
        int4 r4 = q[i];
        unsigned u0 = g2[(size_t)r4.x * 8 + lane];
        unsigned u1 = g2[(size_t)r4.y * 8 + lane];
        unsigned u2 = g2[(size_t)r4.z * 8 + lane];
        unsigned u3 = g2[(size_t)r4.w * 8 + lane];
        float2 v0 = unpack_bf16x2(u0), v1 = unpack_bf16x2(u1);
        float2 v2 = unpack_bf16x2(u2), v3 = unpack_bf16x2(u3);
        s0 += (v0.x + v1.x) + (v2.x + v3.x);
        s1 += (v0.y + v1.y) + (v2.y + v3.y);
    }
    for (int i = beg + (nq << 2); i < beg + deg; ++i) {
        int r = csr_row[i];
        float2 v = unpack_bf16x2(g2[(size_t)r * 8 + lane]);
        s0 += v.x;
        s1 += v.y;
    }
    float d = dinv[node];
    float2 zv = make_float2(s0 * d, s1 * d);            // channels 2l, 2l+1
    float p[5];
#pragma unroll
    for (int k = 0; k < 5; ++k) p[k] = bs[lane + 8 * k];
#pragma unroll
    for (int i = 0; i < HID; ++i) {
        float zi = __shfl((i & 1) ? zv.y : zv.x, i >> 1, 8);
#pragma unroll
        for (int k = 0; k < 5; ++k) p[k] = fmaf(zi, Ws[i * OUT_CH + lane + 8 * k], p[k]);
    }
    float m = p[0];
#pragma unroll
    for (int k = 1; k < 5; ++k) m = fmaxf(m, p[k]);
#pragma unroll
    for (int off = 4; off; off >>= 1) m = fmaxf(m, __shfl_xor(m, off, 8));
    float s = 0.f;
#pragma unroll
    for (int k = 0; k < 5; ++k) s += expf(p[k] - m);
#pragma unroll
    for (int off = 4; off; off >>= 1) s += __shfl_xor(s, off, 8);
    float lse = m + logf(s);
    float* o = out + (size_t)node * OUT_CH;
#pragma unroll
    for (int k = 0; k < 5; ++k) o[lane + 8 * k] = p[k] - lse;
}

extern "C" void kernel_launch(void* const* d_in, const int* in_sizes, int n_in,
                              void* d_out, int out_size, void* d_ws, size_t ws_size,
                              hipStream_t stream) {
    const float* x  = (const float*)d_in[0];
    const int*   ei = (const int*)d_in[1];      // [2, E] int32
    const float* W1 = (const float*)d_in[2];
    const float* b1 = (const float*)d_in[3];
    const float* W2 = (const float*)d_in[4];
    const float* b2 = (const float*)d_in[5];
    float* out = (float*)d_out;

    const int* row = ei;
    const int* col = ei + N_EDGES;

    // ws layout (4-byte units): degi[N] offs[N] sums[512] rank[E] csr_row[E+4N pad] dinv[N] g1[N*8] g2[N*8]
    int*      degi    = (int*)d_ws;
    int*      offs    = degi + N_NODES;
    int*      sums    = offs + N_NODES;
    int*      rank    = sums + 512;
    int*      csr_row = rank + N_EDGES;
    float*    dinv    = (float*)(csr_row + N_EDGES + 4 * N_NODES);
    unsigned* g1      = (unsigned*)(dinv + N_NODES);
    unsigned* g2      = g1 + (size_t)N_NODES * 8;

    hipMemsetAsync(degi, 0, (size_t)N_NODES * sizeof(int), stream);

    const int B = 256;
    const int g8 = (N_NODES * 8 + B - 1) / B;   // 3125

    fused_count_gemm_kernel<<<GEMM_BLOCKS + EDGE_BLOCKS, B, 0, stream>>>(x, W1, g1, col, degi, rank);
    scan_chunk_kernel<<<NCHUNK, CHUNK, 0, stream>>>(degi, offs, sums, dinv, N_NODES);
    scan_sums_kernel<<<1, 512, 0, stream>>>(sums, NCHUNK);
    add_base_kernel<<<NCHUNK, CHUNK, 0, stream>>>(offs, sums, N_NODES);
    fill_kernel<<<EDGE_BLOCKS, B, 0, stream>>>(row, col, offs, rank, csr_row);
    gather1_kernel<<<g8, B, 0, stream>>>(offs, degi, csr_row, g1, dinv, b1, g2, N_NODES);
    gather2_kernel<<<g8, B, 0, stream>>>(offs, degi, csr_row, g2, dinv, W2, b2, out, N_NODES);
}

// Round 8
// 454.420 us; speedup vs baseline: 12.3886x; 1.0412x over previous
//
#include <hip/hip_runtime.h>

#define N_NODES 100000
#define N_EDGES 3200000
#define IN_CH 256
#define HID 16
#define OUT_CH 40
#define CHUNK 256
#define NCHUNK ((N_NODES + CHUNK - 1) / CHUNK)   // 391

#define GEMM_BLOCKS 391          // ceil(100000/256)
#define EDGE_BLOCKS 3125         // 3125*256*4 == 3,200,000 exactly
#define EDGE_STRIDE (EDGE_BLOCKS * 256)

// ---- bf16x2 pack/unpack (RNE) ----
__device__ inline unsigned pack_bf16x2(float a, float b) {
    unsigned ua = __builtin_bit_cast(unsigned, a);
    unsigned ub = __builtin_bit_cast(unsigned, b);
    ua = (ua + 0x7FFFu + ((ua >> 16) & 1u)) >> 16;
    ub = (ub + 0x7FFFu + ((ub >> 16) & 1u)) >> 16;
    return ua | (ub << 16);
}
__device__ inline float2 unpack_bf16x2(unsigned u) {
    float lo = __builtin_bit_cast(float, u << 16);
    float hi = __builtin_bit_cast(float, u & 0xFFFF0000u);
    return make_float2(lo, hi);
}

// ---------------- fused: blocks [0,GEMM_BLOCKS) do g1 = bf16(x@W1) (unscaled);
//                  blocks [GEMM_BLOCKS, +EDGE_BLOCKS) do histogram+rank ----------------
__global__ __launch_bounds__(256, 8)
void fused_count_gemm_kernel(const float* __restrict__ x, const float* __restrict__ W1,
                             unsigned* __restrict__ g1,
                             const int* __restrict__ col, int* __restrict__ degi,
                             int* __restrict__ rank) {
    __shared__ float Ws[IN_CH * HID];   // 16 KB
    int bid = blockIdx.x;
    if (bid < GEMM_BLOCKS) {
        for (int i = threadIdx.x; i < IN_CH * HID; i += blockDim.x) Ws[i] = W1[i];
        __syncthreads();
        int r = bid * 256 + threadIdx.x;
        if (r >= N_NODES) return;
        float acc[HID];
#pragma unroll
        for (int j = 0; j < HID; ++j) acc[j] = 0.f;
        const float4* xr = (const float4*)(x + (size_t)r * IN_CH);
#pragma unroll 4
        for (int c = 0; c < IN_CH / 4; ++c) {
            float4 v = xr[c];
            const float* w = &Ws[c * 4 * HID];
#pragma unroll
            for (int j = 0; j < HID; ++j)
                acc[j] += v.x * w[j] + v.y * w[HID + j] + v.z * w[2 * HID + j] + v.w * w[3 * HID + j];
        }
        uint4 o0, o1;
        o0.x = pack_bf16x2(acc[0], acc[1]);
        o0.y = pack_bf16x2(acc[2], acc[3]);
        o0.z = pack_bf16x2(acc[4], acc[5]);
        o0.w = pack_bf16x2(acc[6], acc[7]);
        o1.x = pack_bf16x2(acc[8], acc[9]);
        o1.y = pack_bf16x2(acc[10], acc[11]);
        o1.z = pack_bf16x2(acc[12], acc[13]);
        o1.w = pack_bf16x2(acc[14], acc[15]);
        uint4* o = (uint4*)(g1 + (size_t)r * 8);
        o[0] = o0;
        o[1] = o1;
    } else {
        int e0 = (bid - GEMM_BLOCKS) * 256 + threadIdx.x;
#pragma unroll
        for (int k = 0; k < 4; ++k) {
            int e = e0 + k * EDGE_STRIDE;
            rank[e] = atomicAdd(&degi[col[e]], 1);
        }
    }
}

// ---------------- scale g1 in place by dinv[node] = rsqrt(deg+1) ----------------
// one uint4 (8 channels) per thread; node = t >> 1
__global__ void scale_g1_kernel(unsigned* __restrict__ g1, const int* __restrict__ degi, int N2) {
    int t = blockIdx.x * blockDim.x + threadIdx.x;
    if (t >= N2) return;
    float d = rsqrtf((float)degi[t >> 1] + 1.0f);
    uint4* p = (uint4*)(g1) + t;
    uint4 v = *p;
    float2 a = unpack_bf16x2(v.x), b = unpack_bf16x2(v.y);
    float2 c = unpack_bf16x2(v.z), e = unpack_bf16x2(v.w);
    v.x = pack_bf16x2(a.x * d, a.y * d);
    v.y = pack_bf16x2(b.x * d, b.y * d);
    v.z = pack_bf16x2(c.x * d, c.y * d);
    v.w = pack_bf16x2(e.x * d, e.y * d);
    *p = v;
}

// ---------------- exclusive scan over PADDED degi ----------------
// offs are multiples of 4 -> every node's CSR segment starts 16B-aligned.
__global__ void scan_chunk_kernel(const int* __restrict__ in, int* __restrict__ out,
                                  int* __restrict__ sums, int N) {
    __shared__ int buf[2][CHUNK];
    int t = threadIdx.x;
    int gid = blockIdx.x * CHUNK + t;
    int d = (gid < N) ? in[gid] : 0;
    int v = (d + 3) & ~3;                       // padded degree
    int src = 0;
    buf[0][t] = v;
    __syncthreads();
    for (int off = 1; off < CHUNK; off <<= 1) {
        int val = buf[src][t];
        if (t >= off) val += buf[src][t - off];
        buf[src ^ 1][t] = val;
        src ^= 1;
        __syncthreads();
    }
    int inc = buf[src][t];
    if (gid < N) out[gid] = inc - v;            // exclusive
    if (t == CHUNK - 1) sums[blockIdx.x] = inc; // chunk total
}

__global__ void scan_sums_kernel(int* __restrict__ sums, int n) {
    __shared__ int buf[2][512];
    int t = threadIdx.x;
    int v = (t < n) ? sums[t] : 0;
    int src = 0;
    buf[0][t] = v;
    __syncthreads();
    for (int off = 1; off < 512; off <<= 1) {
        int val = buf[src][t];
        if (t >= off) val += buf[src][t - off];
        buf[src ^ 1][t] = val;
        src ^= 1;
        __syncthreads();
    }
    if (t < n) sums[t] = buf[src][t] - v;       // exclusive, in place
}

__global__ void add_base_kernel(int* __restrict__ offs, const int* __restrict__ sums, int N) {
    int gid = blockIdx.x * CHUNK + threadIdx.x;
    if (gid < N) offs[gid] += sums[blockIdx.x];
}

// ---------------- CSR fill, atomic-free, 4 edges/thread ----------------
__global__ void fill_kernel(const int* __restrict__ row, const int* __restrict__ col,
                            const int* __restrict__ offs, const int* __restrict__ rank,
                            int* __restrict__ csr_row) {
    int e0 = blockIdx.x * blockDim.x + threadIdx.x;
#pragma unroll
    for (int k = 0; k < 4; ++k) {
        int e = e0 + k * EDGE_STRIDE;
        csr_row[offs[col[e]] + rank[e]] = row[e];
    }
}

// ---------------- gather layer1: unroll-8; g2 = relu(d*sum+b1)*d ----------------
// 8 lanes per node; lane holds channels 2l, 2l+1; g1 pre-scaled by dinv
__global__ void gather1_kernel(const int* __restrict__ offs, const int* __restrict__ degi,
                               const int* __restrict__ csr_row, const unsigned* __restrict__ g1,
                               const float* __restrict__ b1, unsigned* __restrict__ g2, int N) {
    int t = blockIdx.x * blockDim.x + threadIdx.x;
    int node = t >> 3, lane = t & 7;
    if (node >= N) return;
    int beg = offs[node];                       // 16B-aligned (padded scan)
    int deg = degi[node];
    float d = rsqrtf((float)deg + 1.0f);
    float2 self = unpack_bf16x2(g1[(size_t)node * 8 + lane]);
    float s0 = self.x, s1 = self.y;             // g1 already scaled by dinv
    const int4* q = (const int4*)(csr_row + beg);
    int nq8 = deg >> 3;
    for (int i = 0; i < nq8; ++i) {
        int4 ra = q[2 * i], rb = q[2 * i + 1];
        unsigned u0 = g1[(size_t)ra.x * 8 + lane];
        unsigned u1 = g1[(size_t)ra.y * 8 + lane];
        unsigned u2 = g1[(size_t)ra.z * 8 + lane];
        unsigned u3 = g1[(size_t)ra.w * 8 + lane];
        unsigned u4 = g1[(size_t)rb.x * 8 + lane];
        unsigned u5 = g1[(size_t)rb.y * 8 + lane];
        unsigned u6 = g1[(size_t)rb.z * 8 + lane];
        unsigned u7 = g1[(size_t)rb.w * 8 + lane];
        float2 v0 = unpack_bf16x2(u0), v1 = unpack_bf16x2(u1);
        float2 v2 = unpack_bf16x2(u2), v3 = unpack_bf16x2(u3);
        float2 v4 = unpack_bf16x2(u4), v5 = unpack_bf16x2(u5);
        float2 v6 = unpack_bf16x2(u6), v7 = unpack_bf16x2(u7);
        s0 += ((v0.x + v1.x) + (v2.x + v3.x)) + ((v4.x + v5.x) + (v6.x + v7.x));
        s1 += ((v0.y + v1.y) + (v2.y + v3.y)) + ((v4.y + v5.y) + (v6.y + v7.y));
    }
    int done = nq8 << 3;
    if (deg - done >= 4) {
        int4 ra = q[2 * nq8];
        unsigned u0 = g1[(size_t)ra.x * 8 + lane];
        unsigned u1 = g1[(size_t)ra.y * 8 + lane];
        unsigned u2 = g1[(size_t)ra.z * 8 + lane];
        unsigned u3 = g1[(size_t)ra.w * 8 + lane];
        float2 v0 = unpack_bf16x2(u0), v1 = unpack_bf16x2(u1);
        float2 v2 = unpack_bf16x2(u2), v3 = unpack_bf16x2(u3);
        s0 += (v0.x + v1.x) + (v2.x + v3.x);
        s1 += (v0.y + v1.y) + (v2.y + v3.y);
        done += 4;
    }
    for (int i = beg + done; i < beg + deg; ++i) {
        int r = csr_row[i];
        float2 v = unpack_bf16x2(g1[(size_t)r * 8 + lane]);
        s0 += v.x;
        s1 += v.y;
    }
    float h0 = fmaxf(fmaf(s0, d, b1[2 * lane]), 0.f);
    float h1 = fmaxf(fmaf(s1, d, b1[2 * lane + 1]), 0.f);
    g2[(size_t)node * 8 + lane] = pack_bf16x2(h0 * d, h1 * d);   // pre-scaled for layer 2
}

// ---------------- gather layer2 + W2 + log_softmax, unroll-8 ----------------
// 8 lanes per node; lane l computes output cols l, l+8, l+16, l+24, l+32
__global__ void gather2_kernel(const int* __restrict__ offs, const int* __restrict__ degi,
                               const int* __restrict__ csr_row, const unsigned* __restrict__ g2,
                               const float* __restrict__ W2, const float* __restrict__ b2,
                               float* __restrict__ out, int N) {
    __shared__ float Ws[HID * OUT_CH];  // 2.5 KB
    __shared__ float bs[OUT_CH];
    for (int i = threadIdx.x; i < HID * OUT_CH; i += blockDim.x) Ws[i] = W2[i];
    for (int i = threadIdx.x; i < OUT_CH; i += blockDim.x) bs[i] = b2[i];
    __syncthreads();
    int t = blockIdx.x * blockDim.x + threadIdx.x;
    int node = t >> 3, lane = t & 7;
    if (node >= N) return;
    int beg = offs[node];
    int deg = degi[node];
    float2 self = unpack_bf16x2(g2[(size_t)node * 8 + lane]);
    float s0 = self.x, s1 = self.y;
    const int4* q = (const int4*)(csr_row + beg);
    int nq8 = deg >> 3;
    for (int i = 0; i < nq8; ++i) {
        int4 ra = q[2 * i], rb = q[2 * i + 1];
        unsigned u0 = g2[(size_t)ra.x * 8 + lane];
        unsigned u1 = g2[(size_t)ra.y * 8 + lane];
        unsigned u2 = g2[(size_t)ra.z * 8 + lane];
        unsigned u3 = g2[(size_t)ra.w * 8 + lane];
        unsigned u4 = g2[(size_t)rb.x * 8 + lane];
        unsigned u5 = g2[(size_t)rb.y * 8 + lane];
        unsigned u6 = g2[(size_t)rb.z * 8 + lane];
        unsigned u7 = g2[(size_t)rb.w * 8 + lane];
        float2 v0 = unpack_bf16x2(u0), v1 = unpack_bf16x2(u1);
        float2 v2 = unpack_bf16x2(u2), v3 = unpack_bf16x2(u3);
        float2 v4 = unpack_bf16x2(u4), v5 = unpack_bf16x2(u5);
        float2 v6 = unpack_bf16x2(u6), v7 = unpack_bf16x2(u7);
        s0 += ((v0.x + v1.x) + (v2.x + v3.x)) + ((v4.x + v5.x) + (v6.x + v7.x));
        s1 += ((v0.y + v1.y) + (v2.y + v3.y)) + ((v4.y + v5.y) + (v6.y + v7.y));
    }
    int done = nq8 << 3;
    if (deg - done >= 4) {
        int4 ra = q[2 * nq8];
        unsigned u0 = g2[(size_t)ra.x * 8 + lane];
        unsigned u1 = g2[(size_t)ra.y * 8 + lane];
        unsigned u2 = g2[(size_t)ra.z * 8 + lane];
        unsigned u3 = g2[(size_t)ra.w * 8 + lane];
        float2 v0 = unpack_bf16x2(u0), v1 = unpack_bf16x2(u1);
        float2 v2 = unpack_bf16x2(u2), v3 = unpack_bf16x2(u3);
        s0 += (v0.x + v1.x) + (v2.x + v3.x);
        s1 += (v0.y + v1.y) + (v2.y + v3.y);
        done += 4;
    }
    for (int i = beg + done; i < beg + deg; ++i) {
        int r = csr_row[i];
        float2 v = unpack_bf16x2(g2[(size_t)r * 8 + lane]);
        s0 += v.x;
        s1 += v.y;
    }
    float d = rsqrtf((float)deg + 1.0f);
    float2 zv = make_float2(s0 * d, s1 * d);            // channels 2l, 2l+1
    float p[5];
#pragma unroll
    for (int k = 0; k < 5; ++k) p[k] = bs[lane + 8 * k];
#pragma unroll
    for (int i = 0; i < HID; ++i) {
        float zi = __shfl((i & 1) ? zv.y : zv.x, i >> 1, 8);
#pragma unroll
        for (int k = 0; k < 5; ++k) p[k] = fmaf(zi, Ws[i * OUT_CH + lane + 8 * k], p[k]);
    }
    float m = p[0];
#pragma unroll
    for (int k = 1; k < 5; ++k) m = fmaxf(m, p[k]);
#pragma unroll
    for (int off = 4; off; off >>= 1) m = fmaxf(m, __shfl_xor(m, off, 8));
    float s = 0.f;
#pragma unroll
    for (int k = 0; k < 5; ++k) s += expf(p[k] - m);
#pragma unroll
    for (int off = 4; off; off >>= 1) s += __shfl_xor(s, off, 8);
    float lse = m + logf(s);
    float* o = out + (size_t)node * OUT_CH;
#pragma unroll
    for (int k = 0; k < 5; ++k) o[lane + 8 * k] = p[k] - lse;
}

extern "C" void kernel_launch(void* const* d_in, const int* in_sizes, int n_in,
                              void* d_out, int out_size, void* d_ws, size_t ws_size,
                              hipStream_t stream) {
    const float* x  = (const float*)d_in[0];
    const int*   ei = (const int*)d_in[1];      // [2, E] int32
    const float* W1 = (const float*)d_in[2];
    const float* b1 = (const float*)d_in[3];
    const float* W2 = (const float*)d_in[4];
    const float* b2 = (const float*)d_in[5];
    float* out = (float*)d_out;

    const int* row = ei;
    const int* col = ei + N_EDGES;

    // ws layout (4-byte units): degi[N] offs[N] sums[512] rank[E] csr_row[E+4N pad] g1[N*8] g2[N*8]
    int*      degi    = (int*)d_ws;
    int*      offs    = degi + N_NODES;
    int*      sums    = offs + N_NODES;
    int*      rank    = sums + 512;
    int*      csr_row = rank + N_EDGES;
    unsigned* g1      = (unsigned*)(csr_row + N_EDGES + 4 * N_NODES);
    unsigned* g2      = g1 + (size_t)N_NODES * 8;

    hipMemsetAsync(degi, 0, (size_t)N_NODES * sizeof(int), stream);

    const int B = 256;
    const int g8 = (N_NODES * 8 + B - 1) / B;   // 3125

    fused_count_gemm_kernel<<<GEMM_BLOCKS + EDGE_BLOCKS, B, 0, stream>>>(x, W1, g1, col, degi, rank);
    scale_g1_kernel<<<(N_NODES * 2 + B - 1) / B, B, 0, stream>>>(g1, degi, N_NODES * 2);
    scan_chunk_kernel<<<NCHUNK, CHUNK, 0, stream>>>(degi, offs, sums, N_NODES);
    scan_sums_kernel<<<1, 512, 0, stream>>>(sums, NCHUNK);
    add_base_kernel<<<NCHUNK, CHUNK, 0, stream>>>(offs, sums, N_NODES);
    fill_kernel<<<EDGE_BLOCKS, B, 0, stream>>>(row, col, offs, rank, csr_row);
    gather1_kernel<<<g8, B, 0, stream>>>(offs, degi, csr_row, g1, b1, g2, N_NODES);
    gather2_kernel<<<g8, B, 0, stream>>>(offs, degi, csr_row, g2, W2, b2, out, N_NODES);
}

// Round 9
// 344.170 us; speedup vs baseline: 16.3571x; 1.3203x over previous
//
#include <hip/hip_runtime.h>

#define N_NODES 100000
#define N_EDGES 3200000
#define IN_CH 256
#define HID 16
#define OUT_CH 40

#define NBKT 391            // ceil(N_NODES/256); bucket = col >> 8
#define ABLK 512            // histogram/scatter blocks
#define EPB  6250           // edges per block: 512*6250 == 3,200,000
#define BSTRIDE 10240       // CSR slots per bucket (mean padded ~8568; ~18 sigma margin)
#define GEMM_BLOCKS 391     // ceil(100000/256)

// ---- bf16x2 pack/unpack (RNE) ----
__device__ inline unsigned pack_bf16x2(float a, float b) {
    unsigned ua = __builtin_bit_cast(unsigned, a);
    unsigned ub = __builtin_bit_cast(unsigned, b);
    ua = (ua + 0x7FFFu + ((ua >> 16) & 1u)) >> 16;
    ub = (ub + 0x7FFFu + ((ub >> 16) & 1u)) >> 16;
    return ua | (ub << 16);
}
__device__ inline float2 unpack_bf16x2(unsigned u) {
    float lo = __builtin_bit_cast(float, u << 16);
    float hi = __builtin_bit_cast(float, u & 0xFFFF0000u);
    return make_float2(lo, hi);
}

// ---------------- A: blocks [0,GEMM_BLOCKS) g1 = bf16(x@W1) (unscaled);
//                  blocks [GEMM_BLOCKS,+ABLK) LDS bucket histogram -> cnt[bkt][blk] ----------------
__global__ __launch_bounds__(256, 8)
void fused_gemm_hist_kernel(const float* __restrict__ x, const float* __restrict__ W1,
                            unsigned* __restrict__ g1, const int* __restrict__ col,
                            int* __restrict__ cnt) {
    __shared__ float Ws[IN_CH * HID];   // 16 KB; aliased as int histogram in edge branch
    int bid = blockIdx.x;
    if (bid < GEMM_BLOCKS) {
        for (int i = threadIdx.x; i < IN_CH * HID; i += blockDim.x) Ws[i] = W1[i];
        __syncthreads();
        int r = bid * 256 + threadIdx.x;
        if (r >= N_NODES) return;
        float acc[HID];
#pragma unroll
        for (int j = 0; j < HID; ++j) acc[j] = 0.f;
        const float4* xr = (const float4*)(x + (size_t)r * IN_CH);
#pragma unroll 4
        for (int c = 0; c < IN_CH / 4; ++c) {
            float4 v = xr[c];
            const float* w = &Ws[c * 4 * HID];
#pragma unroll
            for (int j = 0; j < HID; ++j)
                acc[j] += v.x * w[j] + v.y * w[HID + j] + v.z * w[2 * HID + j] + v.w * w[3 * HID + j];
        }
        uint4 o0, o1;
        o0.x = pack_bf16x2(acc[0], acc[1]);
        o0.y = pack_bf16x2(acc[2], acc[3]);
        o0.z = pack_bf16x2(acc[4], acc[5]);
        o0.w = pack_bf16x2(acc[6], acc[7]);
        o1.x = pack_bf16x2(acc[8], acc[9]);
        o1.y = pack_bf16x2(acc[10], acc[11]);
        o1.z = pack_bf16x2(acc[12], acc[13]);
        o1.w = pack_bf16x2(acc[14], acc[15]);
        uint4* o = (uint4*)(g1 + (size_t)r * 8);
        o[0] = o0;
        o[1] = o1;
    } else {
        int* h = (int*)Ws;
        int blk = bid - GEMM_BLOCKS;
        for (int i = threadIdx.x; i < NBKT; i += 256) h[i] = 0;
        __syncthreads();
        int base_e = blk * EPB;
        for (int i = threadIdx.x; i < EPB; i += 256)
            atomicAdd(&h[col[base_e + i] >> 8], 1);
        __syncthreads();
        for (int i = threadIdx.x; i < NBKT; i += 256) cnt[i * ABLK + blk] = h[i];
    }
}

// ---------------- B: per-bucket exclusive scan over blocks; cnt[b][t] -> excl, tot -> bkt_tot ----------------
__global__ void colscan_kernel(int* __restrict__ cnt, int* __restrict__ bkt_tot) {
    __shared__ int buf[2][ABLK];
    int b = blockIdx.x, t = threadIdx.x;
    int v = cnt[b * ABLK + t];
    int src = 0;
    buf[0][t] = v;
    __syncthreads();
    for (int off = 1; off < ABLK; off <<= 1) {
        int val = buf[src][t];
        if (t >= off) val += buf[src][t - off];
        buf[src ^ 1][t] = val;
        src ^= 1;
        __syncthreads();
    }
    int inc = buf[src][t];
    cnt[b * ABLK + t] = inc - v;                // exclusive within bucket
    if (t == ABLK - 1) bkt_tot[b] = inc;        // bucket total
}

// ---------------- C: exclusive scan of bkt_tot in place (n<=512) ----------------
__global__ void scan_sums_kernel(int* __restrict__ sums, int n) {
    __shared__ int buf[2][512];
    int t = threadIdx.x;
    int v = (t < n) ? sums[t] : 0;
    int src = 0;
    buf[0][t] = v;
    __syncthreads();
    for (int off = 1; off < 512; off <<= 1) {
        int val = buf[src][t];
        if (t >= off) val += buf[src][t - off];
        buf[src ^ 1][t] = val;
        src ^= 1;
        __syncthreads();
    }
    if (t < n) sums[t] = buf[src][t] - v;
}

// ---------------- D: scatter packed (row<<8 | col&255) into bucket-major ebuf ----------------
__global__ __launch_bounds__(256, 8)
void scatter_pairs_kernel(const int* __restrict__ row, const int* __restrict__ col,
                          const int* __restrict__ cnt, const int* __restrict__ bkt_base,
                          unsigned* __restrict__ ebuf) {
    __shared__ int h[NBKT];
    int blk = blockIdx.x;
    for (int i = threadIdx.x; i < NBKT; i += 256) h[i] = cnt[i * ABLK + blk] + bkt_base[i];
    __syncthreads();
    int base_e = blk * EPB;
    for (int i = threadIdx.x; i < EPB; i += 256) {
        int e = base_e + i;
        int c = col[e];
        int pos = atomicAdd(&h[c >> 8], 1);
        ebuf[pos] = ((unsigned)row[e] << 8) | (unsigned)(c & 255);
    }
}

// ---------------- E: per-bucket CSR build (LDS count -> scan -> place); writes degi/offs ----------------
__global__ void bucket_csr_kernel(const unsigned* __restrict__ ebuf, const int* __restrict__ bkt_base,
                                  int* __restrict__ csr_row, int* __restrict__ degi,
                                  int* __restrict__ offs) {
    __shared__ int ccnt[256];
    __shared__ int cbase[256];
    __shared__ int sbuf[2][256];
    int b = blockIdx.x, t = threadIdx.x;
    ccnt[t] = 0;
    __syncthreads();
    int s = bkt_base[b];
    int e = (b + 1 < NBKT) ? bkt_base[b + 1] : N_EDGES;
    for (int i = s + t; i < e; i += 256)
        atomicAdd(&ccnt[ebuf[i] & 255u], 1);
    __syncthreads();
    int d = ccnt[t];
    int pd = (d + 3) & ~3;                      // padded degree (16B-aligned segments)
    int src = 0;
    sbuf[0][t] = pd;
    __syncthreads();
    for (int off = 1; off < 256; off <<= 1) {
        int val = sbuf[src][t];
        if (t >= off) val += sbuf[src][t - off];
        sbuf[src ^ 1][t] = val;
        src ^= 1;
        __syncthreads();
    }
    int base = b * BSTRIDE + sbuf[src][t] - pd; // exclusive prefix
    cbase[t] = base;
    int node = (b << 8) + t;
    if (node < N_NODES) {
        degi[node] = d;
        offs[node] = base;
    }
    __syncthreads();
    for (int i = s + t; i < e; i += 256) {
        unsigned p = ebuf[i];
        int pos = atomicAdd(&cbase[p & 255u], 1);
        csr_row[pos] = (int)(p >> 8);
    }
}

// ---------------- scale g1 in place by dinv = rsqrt(deg+1); one uint4 per thread ----------------
__global__ void scale_g1_kernel(unsigned* __restrict__ g1, const int* __restrict__ degi, int N2) {
    int t = blockIdx.x * blockDim.x + threadIdx.x;
    if (t >= N2) return;
    float d = rsqrtf((float)degi[t >> 1] + 1.0f);
    uint4* p = (uint4*)(g1) + t;
    uint4 v = *p;
    float2 a = unpack_bf16x2(v.x), b = unpack_bf16x2(v.y);
    float2 c = unpack_bf16x2(v.z), e = unpack_bf16x2(v.w);
    v.x = pack_bf16x2(a.x * d, a.y * d);
    v.y = pack_bf16x2(b.x * d, b.y * d);
    v.z = pack_bf16x2(c.x * d, c.y * d);
    v.w = pack_bf16x2(e.x * d, e.y * d);
    *p = v;
}

// ---------------- gather layer1: unroll-8; g2 = relu(d*sum+b1)*d ----------------
__global__ void gather1_kernel(const int* __restrict__ offs, const int* __restrict__ degi,
                               const int* __restrict__ csr_row, const unsigned* __restrict__ g1,
                               const float* __restrict__ b1, unsigned* __restrict__ g2, int N) {
    int t = blockIdx.x * blockDim.x + threadIdx.x;
    int node = t >> 3, lane = t & 7;
    if (node >= N) return;
    int beg = offs[node];
    int deg = degi[node];
    float d = rsqrtf((float)deg + 1.0f);
    float2 self = unpack_bf16x2(g1[(size_t)node * 8 + lane]);
    float s0 = self.x, s1 = self.y;
    const int4* q = (const int4*)(csr_row + beg);
    int nq8 = deg >> 3;
    for (int i = 0; i < nq8; ++i) {
        int4 ra = q[2 * i], rb = q[2 * i + 1];
        unsigned u0 = g1[(size_t)ra.x * 8 + lane];
        unsigned u1 = g1[(size_t)ra.y * 8 + lane];
        unsigned u2 = g1[(size_t)ra.z * 8 + lane];
        unsigned u3 = g1[(size_t)ra.w * 8 + lane];
        unsigned u4 = g1[(size_t)rb.x * 8 + lane];
        unsigned u5 = g1[(size_t)rb.y * 8 + lane];
        unsigned u6 = g1[(size_t)rb.z * 8 + lane];
        unsigned u7 = g1[(size_t)rb.w * 8 + lane];
        float2 v0 = unpack_bf16x2(u0), v1 = unpack_bf16x2(u1);
        float2 v2 = unpack_bf16x2(u2), v3 = unpack_bf16x2(u3);
        float2 v4 = unpack_bf16x2(u4), v5 = unpack_bf16x2(u5);
        float2 v6 = unpack_bf16x2(u6), v7 = unpack_bf16x2(u7);
        s0 += ((v0.x + v1.x) + (v2.x + v3.x)) + ((v4.x + v5.x) + (v6.x + v7.x));
        s1 += ((v0.y + v1.y) + (v2.y + v3.y)) + ((v4.y + v5.y) + (v6.y + v7.y));
    }
    int done = nq8 << 3;
    if (deg - done >= 4) {
        int4 ra = q[2 * nq8];
        unsigned u0 = g1[(size_t)ra.x * 8 + lane];
        unsigned u1 = g1[(size_t)ra.y * 8 + lane];
        unsigned u2 = g1[(size_t)ra.z * 8 + lane];
        unsigned u3 = g1[(size_t)ra.w * 8 + lane];
        float2 v0 = unpack_bf16x2(u0), v1 = unpack_bf16x2(u1);
        float2 v2 = unpack_bf16x2(u2), v3 = unpack_bf16x2(u3);
        s0 += (v0.x + v1.x) + (v2.x + v3.x);
        s1 += (v0.y + v1.y) + (v2.y + v3.y);
        done += 4;
    }
    for (int i = beg + done; i < beg + deg; ++i) {
        int r = csr_row[i];
        float2 v = unpack_bf16x2(g1[(size_t)r * 8 + lane]);
        s0 += v.x;
        s1 += v.y;
    }
    float h0 = fmaxf(fmaf(s0, d, b1[2 * lane]), 0.f);
    float h1 = fmaxf(fmaf(s1, d, b1[2 * lane + 1]), 0.f);
    g2[(size_t)node * 8 + lane] = pack_bf16x2(h0 * d, h1 * d);
}

// ---------------- gather layer2 + W2 + log_softmax, unroll-8 ----------------
__global__ void gather2_kernel(const int* __restrict__ offs, const int* __restrict__ degi,
                               const int* __restrict__ csr_row, const unsigned* __restrict__ g2,
                               const float* __restrict__ W2, const float* __restrict__ b2,
                               float* __restrict__ out, int N) {
    __shared__ float Ws[HID * OUT_CH];
    __shared__ float bs[OUT_CH];
    for (int i = threadIdx.x; i < HID * OUT_CH; i += blockDim.x) Ws[i] = W2[i];
    for (int i = threadIdx.x; i < OUT_CH; i += blockDim.x) bs[i] = b2[i];
    __syncthreads();
    int t = blockIdx.x * blockDim.x + threadIdx.x;
    int node = t >> 3, lane = t & 7;
    if (node >= N) return;
    int beg = offs[node];
    int deg = degi[node];
    float2 self = unpack_bf16x2(g2[(size_t)node * 8 + lane]);
    float s0 = self.x, s1 = self.y;
    const int4* q = (const int4*)(csr_row + beg);
    int nq8 = deg >> 3;
    for (int i = 0; i < nq8; ++i) {
        int4 ra = q[2 * i], rb = q[2 * i + 1];
        unsigned u0 = g2[(size_t)ra.x * 8 + lane];
        unsigned u1 = g2[(size_t)ra.y * 8 + lane];
        unsigned u2 = g2[(size_t)ra.z * 8 + lane];
        unsigned u3 = g2[(size_t)ra.w * 8 + lane];
        unsigned u4 = g2[(size_t)rb.x * 8 + lane];
        unsigned u5 = g2[(size_t)rb.y * 8 + lane];
        unsigned u6 = g2[(size_t)rb.z * 8 + lane];
        unsigned u7 = g2[(size_t)rb.w * 8 + lane];
        float2 v0 = unpack_bf16x2(u0), v1 = unpack_bf16x2(u1);
        float2 v2 = unpack_bf16x2(u2), v3 = unpack_bf16x2(u3);
        float2 v4 = unpack_bf16x2(u4), v5 = unpack_bf16x2(u5);
        float2 v6 = unpack_bf16x2(u6), v7 = unpack_bf16x2(u7);
        s0 += ((v0.x + v1.x) + (v2.x + v3.x)) + ((v4.x + v5.x) + (v6.x + v7.x));
        s1 += ((v0.y + v1.y) + (v2.y + v3.y)) + ((v4.y + v5.y) + (v6.y + v7.y));
    }
    int done = nq8 << 3;
    if (deg - done >= 4) {
        int4 ra = q[2 * nq8];
        unsigned u0 = g2[(size_t)ra.x * 8 + lane];
        unsigned u1 = g2[(size_t)ra.y * 8 + lane];
        unsigned u2 = g2[(size_t)ra.z * 8 + lane];
        unsigned u3 = g2[(size_t)ra.w * 8 + lane];
        float2 v0 = unpack_bf16x2(u0), v1 = unpack_bf16x2(u1);
        float2 v2 = unpack_bf16x2(u2), v3 = unpack_bf16x2(u3);
        s0 += (v0.x + v1.x) + (v2.x + v3.x);
        s1 += (v0.y + v1.y) + (v2.y + v3.y);
        done += 4;
    }
    for (int i = beg + done; i < beg + deg; ++i) {
        int r = csr_row[i];
        float2 v = unpack_bf16x2(g2[(size_t)r * 8 + lane]);
        s0 += v.x;
        s1 += v.y;
    }
    float d = rsqrtf((float)deg + 1.0f);
    float2 zv = make_float2(s0 * d, s1 * d);
    float p[5];
#pragma unroll
    for (int k = 0; k < 5; ++k) p[k] = bs[lane + 8 * k];
#pragma unroll
    for (int i = 0; i < HID; ++i) {
        float zi = __shfl((i & 1) ? zv.y : zv.x, i >> 1, 8);
#pragma unroll
        for (int k = 0; k < 5; ++k) p[k] = fmaf(zi, Ws[i * OUT_CH + lane + 8 * k], p[k]);
    }
    float m = p[0];
#pragma unroll
    for (int k = 1; k < 5; ++k) m = fmaxf(m, p[k]);
#pragma unroll
    for (int off = 4; off; off >>= 1) m = fmaxf(m, __shfl_xor(m, off, 8));
    float s = 0.f;
#pragma unroll
    for (int k = 0; k < 5; ++k) s += expf(p[k] - m);
#pragma unroll
    for (int off = 4; off; off >>= 1) s += __shfl_xor(s, off, 8);
    float lse = m + logf(s);
    float* o = out + (size_t)node * OUT_CH;
#pragma unroll
    for (int k = 0; k < 5; ++k) o[lane + 8 * k] = p[k] - lse;
}

extern "C" void kernel_launch(void* const* d_in, const int* in_sizes, int n_in,
                              void* d_out, int out_size, void* d_ws, size_t ws_size,
                              hipStream_t stream) {
    const float* x  = (const float*)d_in[0];
    const int*   ei = (const int*)d_in[1];      // [2, E] int32
    const float* W1 = (const float*)d_in[2];
    const float* b1 = (const float*)d_in[3];
    const float* W2 = (const float*)d_in[4];
    const float* b2 = (const float*)d_in[5];
    float* out = (float*)d_out;

    const int* row = ei;
    const int* col = ei + N_EDGES;

    // ws layout (4-byte units):
    //   cnt[NBKT*ABLK] bkt_tot[512] ebuf[E] csr_row[NBKT*BSTRIDE] degi[N] offs[N] g1[N*8] g2[N*8]
    int*      cnt     = (int*)d_ws;
    int*      bkt_tot = cnt + NBKT * ABLK;
    unsigned* ebuf    = (unsigned*)(bkt_tot + 512);
    int*      csr_row = (int*)(ebuf + N_EDGES);
    int*      degi    = csr_row + NBKT * BSTRIDE;
    int*      offs    = degi + N_NODES;
    unsigned* g1      = (unsigned*)(offs + N_NODES);
    unsigned* g2      = g1 + (size_t)N_NODES * 8;

    const int B = 256;
    const int g8 = (N_NODES * 8 + B - 1) / B;   // 3125

    fused_gemm_hist_kernel<<<GEMM_BLOCKS + ABLK, B, 0, stream>>>(x, W1, g1, col, cnt);
    colscan_kernel<<<NBKT, ABLK, 0, stream>>>(cnt, bkt_tot);
    scan_sums_kernel<<<1, 512, 0, stream>>>(bkt_tot, NBKT);
    scatter_pairs_kernel<<<ABLK, B, 0, stream>>>(row, col, cnt, bkt_tot, ebuf);
    bucket_csr_kernel<<<NBKT, B, 0, stream>>>(ebuf, bkt_tot, csr_row, degi, offs);
    scale_g1_kernel<<<(N_NODES * 2 + B - 1) / B, B, 0, stream>>>(g1, degi, N_NODES * 2);
    gather1_kernel<<<g8, B, 0, stream>>>(offs, degi, csr_row, g1, b1, g2, N_NODES);
    gather2_kernel<<<g8, B, 0, stream>>>(offs, degi, csr_row, g2, W2, b2, out, N_NODES);
}